// Round 5
// baseline (809.587 us; speedup 1.0000x reference)
//
#include <hip/hip_runtime.h>

typedef unsigned int uint;

#define N_USERS 100000
#define N_ITEMS 50000
#define N_NODES 150000
#define N_EDGES 1500000
#define BATCH 4096

__device__ __forceinline__ uint pack_bf16x2(float a, float b) {
    uint ua = __float_as_uint(a);
    uint ub = __float_as_uint(b);
    ua = (ua + 0x7FFFu + ((ua >> 16) & 1u)) >> 16;
    ub = (ub + 0x7FFFu + ((ub >> 16) & 1u)) >> 16;
    return ua | (ub << 16);
}
__device__ __forceinline__ float bf_lo(uint u) { return __uint_as_float(u << 16); }
__device__ __forceinline__ float bf_hi(uint u) { return __uint_as_float(u & 0xFFFF0000u); }

// ======================= bf16 feature cast (concat u,i) =======================
__global__ __launch_bounds__(256) void cast_feats(
    const float* __restrict__ uE, const float* __restrict__ iE,
    uint* __restrict__ Xb)
{
    int g = blockIdx.x * 256 + threadIdx.x;       // one uint = 2 features
    if (g >= N_NODES * 50) return;                // 7.5M
    int e0 = g * 2;
    float a, b;
    if (e0 < N_USERS * 100) { a = uE[e0]; b = uE[e0 + 1]; }
    else { a = iE[e0 - N_USERS * 100]; b = iE[e0 - N_USERS * 100 + 1]; }
    Xb[g] = pack_bf16x2(a, b);
}

// ======================= CSR construction =======================
__global__ __launch_bounds__(256) void hist_kernel(
    const int* __restrict__ rows, int* __restrict__ deg, int E)
{
    int e = blockIdx.x * 256 + threadIdx.x;
    if (e < E) atomicAdd(&deg[rows[e]], 1);
}

__global__ __launch_bounds__(256) void scan_block(
    const int* __restrict__ deg, int* __restrict__ ptr,
    int* __restrict__ bsum, int n)
{
    __shared__ int s[256];
    int t = threadIdx.x;
    int i = blockIdx.x * 256 + t;
    int v = (i < n) ? deg[i] : 0;
    s[t] = v; __syncthreads();
    for (int off = 1; off < 256; off <<= 1) {
        int x = (t >= off) ? s[t - off] : 0;
        __syncthreads();
        s[t] += x;
        __syncthreads();
    }
    if (i < n) ptr[i] = s[t] - v;
    if (t == 255) bsum[blockIdx.x] = s[255];
}

__global__ __launch_bounds__(1024) void scan_tops(int* __restrict__ bsum, int nb)
{
    __shared__ int s[1024];
    int t = threadIdx.x;
    int v = (t < nb) ? bsum[t] : 0;
    s[t] = v; __syncthreads();
    for (int off = 1; off < 1024; off <<= 1) {
        int x = (t >= off) ? s[t - off] : 0;
        __syncthreads();
        s[t] += x;
        __syncthreads();
    }
    if (t < nb) bsum[t] = s[t] - v;
}

__global__ __launch_bounds__(256) void scan_apply(
    int* __restrict__ ptr, const int* __restrict__ bsum,
    int* __restrict__ pos, int n)
{
    int i = blockIdx.x * 256 + threadIdx.x;
    if (i < n) {
        int p = ptr[i] + bsum[i >> 8];
        ptr[i] = p;
        pos[i] = p;
    }
}

__global__ __launch_bounds__(256) void scatter_edges(
    const int* __restrict__ rows, const int* __restrict__ cols,
    const float* __restrict__ vals, int* __restrict__ pos,
    int2* __restrict__ ep, int E)
{
    int e = blockIdx.x * 256 + threadIdx.x;
    if (e < E) {
        int r = rows[e];
        int p = atomicAdd(&pos[r], 1);
        ep[p] = make_int2(cols[e], __float_as_int(vals[e]));
    }
}

// ============== selMap + needed-row marking =====================
__global__ __launch_bounds__(256) void build_selmap(
    const int* __restrict__ userIdx, const int* __restrict__ itemIdx,
    int* __restrict__ selMap)
{
    int i = blockIdx.x * 256 + threadIdx.x;
    if (i < BATCH) selMap[userIdx[i]] = i;
    else if (i < 2 * BATCH) selMap[itemIdx[i - BATCH]] = i;
}

// needed = selected rows  ∪  columns of selected rows' edges
__global__ __launch_bounds__(256) void mark_needed(
    const int* __restrict__ userIdx, const int* __restrict__ itemIdx,
    const int* __restrict__ ptr_, const int* __restrict__ deg_,
    const int2* __restrict__ ep, int* __restrict__ flag)
{
    int i = blockIdx.x * 4 + ((int)threadIdx.x >> 6);
    if (i >= 2 * BATCH) return;
    int lane = threadIdx.x & 63;
    int row = (i < BATCH) ? userIdx[i] : itemIdx[i - BATCH];
    if (lane == 0) flag[row] = 1;
    int st = ptr_[row], d = deg_[row];
    for (int j = lane; j < d; j += 64)
        flag[ep[st + j].x] = 1;
}

__global__ __launch_bounds__(256) void compact_list(
    const int* __restrict__ flag, const int* __restrict__ fpre,
    const int* __restrict__ bsum, int* __restrict__ list,
    int* __restrict__ count, int n)
{
    int i = blockIdx.x * 256 + threadIdx.x;
    if (i < n) {
        int base = fpre[i] + bsum[i >> 8];
        if (flag[i]) list[base] = i;
        if (i == n - 1) *count = base + flag[i];
    }
}

// ======================= SpMM kernels (bf16 gather) =======================
// One 64-lane wave per row; lane j handles features {2j, 2j+1} (P = F/2).

// Pass 1 (F=100): B1b = bf16(L@X); INTb = bf16((L@X) .* X)
__global__ __launch_bounds__(256) void spmm_pass1(
    const int* __restrict__ ptr_, const int* __restrict__ deg_,
    const int2* __restrict__ ep, const uint* __restrict__ Xb,
    uint* __restrict__ B1b, uint* __restrict__ INTb, int N)
{
    constexpr int P = 50;
    int row = blockIdx.x * 4 + ((int)threadIdx.x >> 6);
    if (row >= N) return;
    int lane = threadIdx.x & 63;
    int st = ptr_[row], d = deg_[row];
    float ax = 0.f, ay = 0.f;
    int2 e = (d > 0) ? ep[st] : make_int2(0, 0);
    for (int j = 0; j < d; j++) {
        int c = e.x; float v = __int_as_float(e.y);
        if (j + 1 < d) e = ep[st + j + 1];
        uint bits = (lane < P) ? Xb[(size_t)c * P + lane] : 0u;
        ax = fmaf(v, bf_lo(bits), ax);
        ay = fmaf(v, bf_hi(bits), ay);
    }
    if (lane < P) {
        B1b[(size_t)row * P + lane] = pack_bf16x2(ax, ay);
        uint xb = Xb[(size_t)row * P + lane];
        INTb[(size_t)row * P + lane] = pack_bf16x2(ax * bf_lo(xb), ay * bf_hi(xb));
    }
}

// Pass 2 (F=100): B2b = bf16(L @ INTb)
__global__ __launch_bounds__(256) void spmm_pass2(
    const int* __restrict__ ptr_, const int* __restrict__ deg_,
    const int2* __restrict__ ep, const uint* __restrict__ Xb,
    uint* __restrict__ outB, int N)
{
    constexpr int P = 50;
    int row = blockIdx.x * 4 + ((int)threadIdx.x >> 6);
    if (row >= N) return;
    int lane = threadIdx.x & 63;
    int st = ptr_[row], d = deg_[row];
    float ax = 0.f, ay = 0.f;
    int2 e = (d > 0) ? ep[st] : make_int2(0, 0);
    for (int j = 0; j < d; j++) {
        int c = e.x; float v = __int_as_float(e.y);
        if (j + 1 < d) e = ep[st + j + 1];
        uint bits = (lane < P) ? Xb[(size_t)c * P + lane] : 0u;
        ax = fmaf(v, bf_lo(bits), ax);
        ay = fmaf(v, bf_hi(bits), ay);
    }
    if (lane < P)
        outB[(size_t)row * P + lane] = pack_bf16x2(ax, ay);
}

// Pass 3 (F=80): fp32 out, only over compacted needed-row list
__global__ __launch_bounds__(256) void spmm_bf_list(
    const int* __restrict__ list, const int* __restrict__ count,
    const int* __restrict__ ptr_, const int* __restrict__ deg_,
    const int2* __restrict__ ep, const uint* __restrict__ Xb,
    float* __restrict__ out)
{
    constexpr int P = 40;
    int idx = blockIdx.x * 4 + ((int)threadIdx.x >> 6);
    if (idx >= *count) return;
    int row = list[idx];
    int lane = threadIdx.x & 63;
    int st = ptr_[row], d = deg_[row];
    float ax = 0.f, ay = 0.f;
    int2 e = (d > 0) ? ep[st] : make_int2(0, 0);
    for (int j = 0; j < d; j++) {
        int c = e.x; float v = __int_as_float(e.y);
        if (j + 1 < d) e = ep[st + j + 1];
        uint bits = (lane < P) ? Xb[(size_t)c * P + lane] : 0u;
        ax = fmaf(v, bf_lo(bits), ax);
        ay = fmaf(v, bf_hi(bits), ay);
    }
    if (lane < P)
        ((float2*)(out + (size_t)row * 80))[lane] = make_float2(ax, ay);
}

// Pass 4 (selected rows): outC[i] = sum_e v * (Lx[c] .* F1[c])
__global__ __launch_bounds__(256) void spmm_sel(
    const int* __restrict__ ptr_, const int* __restrict__ deg_,
    const int2* __restrict__ ep,
    const float* __restrict__ Lx, const uint* __restrict__ F1b,
    const int* __restrict__ userIdx, const int* __restrict__ itemIdx,
    float* __restrict__ outC)
{
    constexpr int P = 40;
    int i = blockIdx.x * 4 + ((int)threadIdx.x >> 6);
    if (i >= 2 * BATCH) return;
    int row = (i < BATCH) ? userIdx[i] : itemIdx[i - BATCH];
    int lane = threadIdx.x & 63;
    int st = ptr_[row], d = deg_[row];
    float ax = 0.f, ay = 0.f;
    int2 e = (d > 0) ? ep[st] : make_int2(0, 0);
    for (int j = 0; j < d; j++) {
        int c = e.x; float v = __int_as_float(e.y);
        if (j + 1 < d) e = ep[st + j + 1];
        float2 l = make_float2(0.f, 0.f);
        uint bits = 0u;
        if (lane < P) {
            l = ((const float2*)(Lx + (size_t)c * 80))[lane];
            bits = F1b[(size_t)c * P + lane];
        }
        ax = fmaf(v, l.x * bf_lo(bits), ax);
        ay = fmaf(v, l.y * bf_hi(bits), ay);
    }
    if (lane < P)
        ((float2*)(outC + (size_t)i * 80))[lane] = make_float2(ax, ay);
}

// ------------- Layer-1 fused linear, row-blocked (R=4) --------------------
// F1 = relu((Lx+X)@W + S2@Wi + b + bi); all inputs bf16-packed.
// Writes F1b (bf16, all rows) + F1sel (fp32, selected rows via selMap).
// R=4 rows/thread amortizes LDS weight reads 4x (was the 146us bottleneck).
__global__ __launch_bounds__(256) void gemm_fused1(
    const uint* __restrict__ Lxb, const uint* __restrict__ Xb,
    const uint* __restrict__ S2b,
    const float* __restrict__ W, const float* __restrict__ b,
    const float* __restrict__ Wi, const float* __restrict__ bi,
    const int* __restrict__ selMap,
    uint* __restrict__ F1b, float* __restrict__ F1sel, int N)
{
    constexpr int K = 100, M = 80, TPR = 4, MT = M / TPR, R = 4;
    constexpr int GROUPS = 256 / TPR;            // 64 groups -> 256 rows/block
    __shared__ float sW[K * M];
    __shared__ float sWi[K * M];
    for (int i = threadIdx.x; i < K * M; i += 256) {
        sW[i]  = W[i];
        sWi[i] = Wi[i];
    }
    __syncthreads();

    int g     = (int)threadIdx.x / TPR;
    int mBase = ((int)threadIdx.x % TPR) * MT;
    int row0  = blockIdx.x * (GROUPS * R) + g * R;

    float acc[R][MT];
#pragma unroll
    for (int r = 0; r < R; r++)
#pragma unroll
        for (int m = 0; m < MT; m++) acc[r][m] = 0.0f;

    for (int k4 = 0; k4 < K; k4 += 4) {
        float a[R][4], s[R][4];
#pragma unroll
        for (int r = 0; r < R; r++) {
            int row = row0 + r;
            if (row < N) {
                size_t o = (size_t)row * 50 + (k4 >> 1);
                uint2 lx = *(const uint2*)&Lxb[o];
                uint2 xx = *(const uint2*)&Xb[o];
                uint2 ss = *(const uint2*)&S2b[o];
                a[r][0] = bf_lo(lx.x) + bf_lo(xx.x);
                a[r][1] = bf_hi(lx.x) + bf_hi(xx.x);
                a[r][2] = bf_lo(lx.y) + bf_lo(xx.y);
                a[r][3] = bf_hi(lx.y) + bf_hi(xx.y);
                s[r][0] = bf_lo(ss.x); s[r][1] = bf_hi(ss.x);
                s[r][2] = bf_lo(ss.y); s[r][3] = bf_hi(ss.y);
            } else {
#pragma unroll
                for (int kk = 0; kk < 4; kk++) { a[r][kk] = 0.f; s[r][kk] = 0.f; }
            }
        }
#pragma unroll
        for (int kk = 0; kk < 4; kk++) {
            const float* wk  = &sW[(k4 + kk) * M + mBase];
            const float* wik = &sWi[(k4 + kk) * M + mBase];
#pragma unroll
            for (int m = 0; m < MT; m++) {
                float wv  = wk[m];
                float wiv = wik[m];
#pragma unroll
                for (int r = 0; r < R; r++)
                    acc[r][m] = fmaf(a[r][kk], wv, fmaf(s[r][kk], wiv, acc[r][m]));
            }
        }
    }

#pragma unroll
    for (int r = 0; r < R; r++) {
        int row = row0 + r;
        if (row >= N) continue;
        float vv[MT];
#pragma unroll
        for (int m = 0; m < MT; m++)
            vv[m] = fmaxf(acc[r][m] + b[mBase + m] + bi[mBase + m], 0.0f);

        uint* brow = F1b + (size_t)row * 40 + (mBase >> 1);
#pragma unroll
        for (int m = 0; m < MT; m += 2)
            brow[m >> 1] = pack_bf16x2(vv[m], vv[m + 1]);

        int sm = selMap[row];
        if (sm >= 0) {
            float* orow = F1sel + (size_t)sm * 80 + mBase;
#pragma unroll
            for (int m = 0; m < MT; m++) orow[m] = vv[m];
        }
    }
}

// Layer-2 fused GEMM restricted to sampled rows; X via compact F1sel.
__global__ __launch_bounds__(256) void gemm_fused2_sel(
    const float* __restrict__ Lx, const float* __restrict__ F1sel,
    const int* __restrict__ selMap,
    const float* __restrict__ S2c,
    const float* __restrict__ W, const float* __restrict__ b,
    const float* __restrict__ Wi, const float* __restrict__ bi,
    const int* __restrict__ userIdx, const int* __restrict__ itemIdx,
    float* __restrict__ outC)
{
    constexpr int K = 80, M = 50, TPR = 2, MT = M / TPR;
    __shared__ float sW[K * M];
    __shared__ float sWi[K * M];
    for (int i = threadIdx.x; i < K * M; i += 256) {
        sW[i]  = W[i];
        sWi[i] = Wi[i];
    }
    __syncthreads();

    int i = blockIdx.x * (256 / TPR) + (int)threadIdx.x / TPR;
    int mBase = ((int)threadIdx.x % TPR) * MT;
    if (i >= 2 * BATCH) return;
    int r = (i < BATCH) ? userIdx[i] : itemIdx[i - BATCH];

    const float* xrow = F1sel + (size_t)selMap[r] * K;
    const float* lrow = Lx + (size_t)r * K;
    const float* srow = S2c + (size_t)i * K;

    float acc[MT];
#pragma unroll
    for (int m = 0; m < MT; m++) acc[m] = 0.0f;

    for (int k4 = 0; k4 < K; k4 += 4) {
        float4 lv = *(const float4*)(lrow + k4);
        float4 xv = *(const float4*)(xrow + k4);
        float4 sv = *(const float4*)(srow + k4);
        float a[4] = {lv.x + xv.x, lv.y + xv.y, lv.z + xv.z, lv.w + xv.w};
        float s[4] = {sv.x, sv.y, sv.z, sv.w};
#pragma unroll
        for (int kk = 0; kk < 4; kk++) {
            const float* wk  = &sW[(k4 + kk) * M + mBase];
            const float* wik = &sWi[(k4 + kk) * M + mBase];
#pragma unroll
            for (int m = 0; m < MT; m++)
                acc[m] = fmaf(a[kk], wk[m], fmaf(s[kk], wik[m], acc[m]));
        }
    }

    float* orow = outC + (size_t)i * M + mBase;
#pragma unroll
    for (int m = 0; m < MT; m++)
        orow[m] = fmaxf(acc[m] + b[mBase + m] + bi[mBase + m], 0.0f);
}

// ------------- Plain MLP GEMM ---------------------------------------------
template<int K, int M, int TPR, bool RELU>
__global__ __launch_bounds__(256) void mlp_gemm(
    const float* __restrict__ A,
    const float* __restrict__ W, const float* __restrict__ b,
    float* __restrict__ out, int N)
{
    __shared__ float sW[K * M];
    for (int i = threadIdx.x; i < K * M; i += 256) sW[i] = W[i];
    __syncthreads();

    constexpr int RPB = 256 / TPR;
    constexpr int MT  = M / TPR;
    int r = blockIdx.x * RPB + (int)threadIdx.x / TPR;
    int mBase = ((int)threadIdx.x % TPR) * MT;
    if (r >= N) return;

    const float* arow = A + (size_t)r * K;
    float acc[MT];
#pragma unroll
    for (int m = 0; m < MT; m++) acc[m] = 0.0f;

    for (int k = 0; k < K; k++) {
        float a = arow[k];
#pragma unroll
        for (int m = 0; m < MT; m++)
            acc[m] = fmaf(a, sW[k * M + mBase + m], acc[m]);
    }

    float* orow = out + (size_t)r * M + mBase;
#pragma unroll
    for (int m = 0; m < MT; m++) {
        float vv = acc[m] + b[mBase + m];
        orow[m] = RELU ? fmaxf(vv, 0.0f) : vv;
    }
}

// ------------- Gather final embeddings into [BATCH, 460] ------------------
__global__ __launch_bounds__(128) void gather_embd(
    const int* __restrict__ userIdx, const int* __restrict__ itemIdx,
    const float* __restrict__ uE, const float* __restrict__ iE,
    const float* __restrict__ F1sel, const int* __restrict__ selMap,
    const float* __restrict__ f2c,
    float* __restrict__ emb)
{
    int bi = blockIdx.x;
    int u  = userIdx[bi];
    int it = itemIdx[bi];
    int su = selMap[u];
    int si = selMap[it];
    float* orow = emb + (size_t)bi * 460;
    for (int c = threadIdx.x; c < 460; c += 128) {
        float val;
        if (c < 100) {
            val = (u < N_USERS) ? uE[(size_t)u * 100 + c]
                                : iE[(size_t)(u - N_USERS) * 100 + c];
        } else if (c < 180) {
            val = F1sel[(size_t)su * 80 + (c - 100)];
        } else if (c < 230) {
            val = f2c[(size_t)bi * 50 + (c - 180)];
        } else if (c < 330) {
            int cc = c - 230;
            val = (it < N_USERS) ? uE[(size_t)it * 100 + cc]
                                 : iE[(size_t)(it - N_USERS) * 100 + cc];
        } else if (c < 410) {
            val = F1sel[(size_t)si * 80 + (c - 330)];
        } else {
            val = f2c[(size_t)(BATCH + bi) * 50 + (c - 410)];
        }
        orow[c] = val;
    }
}

extern "C" void kernel_launch(void* const* d_in, const int* in_sizes, int n_in,
                              void* d_out, int out_size, void* d_ws, size_t ws_size,
                              hipStream_t stream) {
    const int*   userIdx = (const int*)d_in[0];
    const int*   itemIdx = (const int*)d_in[1];
    const int*   rows    = (const int*)d_in[2];
    const int*   cols    = (const int*)d_in[3];
    const float* vals    = (const float*)d_in[4];
    const float* uEmbd   = (const float*)d_in[5];
    const float* iEmbd   = (const float*)d_in[6];
    const float* w1      = (const float*)d_in[7];
    const float* b1      = (const float*)d_in[8];
    const float* wi1     = (const float*)d_in[9];
    const float* bi1     = (const float*)d_in[10];
    const float* w2      = (const float*)d_in[11];
    const float* b2      = (const float*)d_in[12];
    const float* wi2     = (const float*)d_in[13];
    const float* bi2     = (const float*)d_in[14];
    const float* t1w     = (const float*)d_in[15];
    const float* t1b     = (const float*)d_in[16];
    const float* t2w     = (const float*)d_in[17];
    const float* t2b     = (const float*)d_in[18];
    const float* t3w     = (const float*)d_in[19];
    const float* t3b     = (const float*)d_in[20];

    // ---- workspace layout (4-byte units); no live aliasing ----
    float* ws = (float*)d_ws;
    float* B1    = ws;                         // 15,000,000 (layer1: B1b bf16 in first 7.5M; layer2: fp32 Lx2 12M)
    uint*  B1b   = (uint*)B1;                  //  7,500,000
    uint*  Xb    = (uint*)(ws + 15000000);     //  7,500,000
    uint*  INTb  = (uint*)(ws + 22500000);     //  7,500,000
    uint*  B2b   = (uint*)(ws + 30000000);     //  7,500,000
    uint*  F1b   = (uint*)(ws + 37500000);     //  6,000,000
    float* F1sel = ws + 43500000;              //    655,360
    float* B2c   = ws + 44155360;              //    655,360
    float* F2c   = ws + 44810720;              //    409,600
    float* EMB   = ws + 45220320;              //  1,884,160
    float* H1    = ws + 47104480;              //    262,144
    float* H2    = ws + 47366624;              //    131,072
    int*   deg   = (int*)(ws + 47497696);      //    150,000
    int*   ptr   = deg + 150000;               //    150,000
    int*   pos   = ptr + 150000;               //    150,000
    int*   bsum  = pos + 150000;               //      1,024
    int2*  ep    = (int2*)(bsum + 1024);       //  1,500,000 int2 (12 MB)
    int*   flag  = (int*)(ep + 1500000);       //    150,000
    int*   fpre  = flag + 150000;              //    150,000
    int*   list  = fpre + 150000;              //    150,000
    int*   bsum2 = list + 150000;              //      1,024
    int*   cnt   = bsum2 + 1024;               //          1
    int*   selMap= cnt + 1;                    //    150,000   (~206 MB total)

    const int E = N_EDGES;
    dim3 blk(256);

    // ---- bf16 feature cast ----
    cast_feats<<<(N_NODES * 50 + 255) / 256, blk, 0, stream>>>(uEmbd, iEmbd, Xb);

    // ---- CSR build ----
    hipMemsetAsync(deg, 0, 150000 * sizeof(int), stream);
    hipMemsetAsync(flag, 0, 150000 * sizeof(int), stream);
    hipMemsetAsync(selMap, 0xFF, 150000 * sizeof(int), stream);
    hist_kernel<<<(E + 255) / 256, blk, 0, stream>>>(rows, deg, E);
    int nScanBlocks = (N_NODES + 255) / 256;            // 586
    scan_block<<<nScanBlocks, blk, 0, stream>>>(deg, ptr, bsum, N_NODES);
    scan_tops<<<1, dim3(1024), 0, stream>>>(bsum, nScanBlocks);
    scan_apply<<<nScanBlocks, blk, 0, stream>>>(ptr, bsum, pos, N_NODES);
    scatter_edges<<<(E + 255) / 256, blk, 0, stream>>>(rows, cols, vals, pos, ep, E);

    // ---- selMap + needed-row marking + compaction ----
    build_selmap<<<(2 * BATCH + 255) / 256, blk, 0, stream>>>(userIdx, itemIdx, selMap);
    mark_needed<<<(2 * BATCH + 3) / 4, blk, 0, stream>>>(
        userIdx, itemIdx, ptr, deg, ep, flag);
    scan_block<<<nScanBlocks, blk, 0, stream>>>(flag, fpre, bsum2, N_NODES);
    scan_tops<<<1, dim3(1024), 0, stream>>>(bsum2, nScanBlocks);
    compact_list<<<nScanBlocks, blk, 0, stream>>>(flag, fpre, bsum2, list, cnt, N_NODES);

    int rowGrid = (N_NODES + 3) / 4;
    int selGrid = (2 * BATCH + 3) / 4;

    // ---- Layer 1 (F = 100) ----
    spmm_pass1<<<rowGrid, blk, 0, stream>>>(ptr, deg, ep, Xb, B1b, INTb, N_NODES);
    spmm_pass2<<<rowGrid, blk, 0, stream>>>(ptr, deg, ep, INTb, B2b, N_NODES);
    {
        int grid = (N_NODES + 255) / 256;     // 256 rows / block
        gemm_fused1<<<grid, blk, 0, stream>>>(
            B1b, Xb, B2b, w1, b1, wi1, bi1, selMap, F1b, F1sel, N_NODES);
    }

    // ---- Layer 2 (F = 80) ----
    spmm_bf_list<<<rowGrid, blk, 0, stream>>>(
        list, cnt, ptr, deg, ep, F1b, B1);
    spmm_sel<<<selGrid, blk, 0, stream>>>(
        ptr, deg, ep, B1, F1b, userIdx, itemIdx, B2c);
    {
        int grid = (2 * BATCH + 127) / 128;
        gemm_fused2_sel<<<grid, blk, 0, stream>>>(
            B1, F1sel, selMap, B2c, w2, b2, wi2, bi2, userIdx, itemIdx, F2c);
    }

    // ---- Gather + MLP ----
    gather_embd<<<BATCH, dim3(128), 0, stream>>>(
        userIdx, itemIdx, uEmbd, iEmbd, F1sel, selMap, F2c, EMB);
    {
        constexpr int TPR = 8;
        int grid = (BATCH + (256 / TPR) - 1) / (256 / TPR);
        mlp_gemm<460, 64, TPR, true><<<grid, blk, 0, stream>>>(
            EMB, t1w, t1b, H1, BATCH);
    }
    {
        constexpr int TPR = 4;
        int grid = (BATCH + (256 / TPR) - 1) / (256 / TPR);
        mlp_gemm<64, 32, TPR, false><<<grid, blk, 0, stream>>>(
            H1, t2w, t2b, H2, BATCH);
    }
    {
        constexpr int TPR = 1;
        int grid = (BATCH + 255) / 256;
        mlp_gemm<32, 1, TPR, false><<<grid, blk, 0, stream>>>(
            H2, t3w, t3b, (float*)d_out, BATCH);
    }
}

// Round 6
// 661.078 us; speedup vs baseline: 1.2246x; 1.2246x over previous
//
#include <hip/hip_runtime.h>

typedef unsigned int uint;
typedef unsigned short ushort_t;
typedef __attribute__((ext_vector_type(4))) float f32x4;
typedef __attribute__((ext_vector_type(8))) short bf16x8;

#define N_USERS 100000
#define N_ITEMS 50000
#define N_NODES 150000
#define N_EDGES 1500000
#define BATCH 4096

__device__ __forceinline__ uint pack_bf16x2(float a, float b) {
    uint ua = __float_as_uint(a);
    uint ub = __float_as_uint(b);
    ua = (ua + 0x7FFFu + ((ua >> 16) & 1u)) >> 16;
    ub = (ub + 0x7FFFu + ((ub >> 16) & 1u)) >> 16;
    return ua | (ub << 16);
}
__device__ __forceinline__ ushort_t cvt_bf16(float a) {
    uint ua = __float_as_uint(a);
    return (ushort_t)((ua + 0x7FFFu + ((ua >> 16) & 1u)) >> 16);
}
__device__ __forceinline__ float bf_lo(uint u) { return __uint_as_float(u << 16); }
__device__ __forceinline__ float bf_hi(uint u) { return __uint_as_float(u & 0xFFFF0000u); }

// ============ bf16 feature cast, padded stride 64 uints (128 bf16) ============
__global__ __launch_bounds__(256) void cast_feats(
    const float* __restrict__ uE, const float* __restrict__ iE,
    uint* __restrict__ Xb)
{
    int g = blockIdx.x * 256 + threadIdx.x;       // one uint = 2 features
    if (g >= N_NODES * 64) return;
    int row = g >> 6, c = g & 63;
    uint outv = 0u;
    if (c < 50) {
        int e0 = c * 2;
        float a, b;
        if (row < N_USERS) { a = uE[(size_t)row * 100 + e0]; b = uE[(size_t)row * 100 + e0 + 1]; }
        else { a = iE[(size_t)(row - N_USERS) * 100 + e0]; b = iE[(size_t)(row - N_USERS) * 100 + e0 + 1]; }
        outv = pack_bf16x2(a, b);
    }
    Xb[g] = outv;
}

// ============ weight prep: wT bf16 [80 cols][64 uints=128 k, zero-padded] =====
__global__ __launch_bounds__(256) void prep_weights(
    const float* __restrict__ W, const float* __restrict__ Wi,
    uint* __restrict__ wtW, uint* __restrict__ wtWi)
{
    int t = blockIdx.x * 256 + threadIdx.x;
    if (t >= 2 * 80 * 64) return;
    const float* src = (t < 80 * 64) ? W : Wi;
    uint* dst = (t < 80 * 64) ? wtW : wtWi;
    int i = t % (80 * 64);
    int col = i >> 6, kk = i & 63;
    int k = kk * 2;
    uint v = 0u;
    if (k < 100) v = pack_bf16x2(src[(size_t)k * 80 + col], src[(size_t)(k + 1) * 80 + col]);
    dst[(size_t)col * 64 + kk] = v;
}

// ======================= CSR construction =======================
__global__ __launch_bounds__(256) void hist_kernel(
    const int* __restrict__ rows, int* __restrict__ deg, int E)
{
    int e = blockIdx.x * 256 + threadIdx.x;
    if (e < E) atomicAdd(&deg[rows[e]], 1);
}

__global__ __launch_bounds__(256) void scan_block(
    const int* __restrict__ deg, int* __restrict__ ptr,
    int* __restrict__ bsum, int n)
{
    __shared__ int s[256];
    int t = threadIdx.x;
    int i = blockIdx.x * 256 + t;
    int v = (i < n) ? deg[i] : 0;
    s[t] = v; __syncthreads();
    for (int off = 1; off < 256; off <<= 1) {
        int x = (t >= off) ? s[t - off] : 0;
        __syncthreads();
        s[t] += x;
        __syncthreads();
    }
    if (i < n) ptr[i] = s[t] - v;
    if (t == 255) bsum[blockIdx.x] = s[255];
}

__global__ __launch_bounds__(1024) void scan_tops(int* __restrict__ bsum, int nb)
{
    __shared__ int s[1024];
    int t = threadIdx.x;
    int v = (t < nb) ? bsum[t] : 0;
    s[t] = v; __syncthreads();
    for (int off = 1; off < 1024; off <<= 1) {
        int x = (t >= off) ? s[t - off] : 0;
        __syncthreads();
        s[t] += x;
        __syncthreads();
    }
    if (t < nb) bsum[t] = s[t] - v;
}

__global__ __launch_bounds__(256) void scan_apply(
    int* __restrict__ ptr, const int* __restrict__ bsum,
    int* __restrict__ pos, int n)
{
    int i = blockIdx.x * 256 + threadIdx.x;
    if (i < n) {
        int p = ptr[i] + bsum[i >> 8];
        ptr[i] = p;
        pos[i] = p;
    }
}

__global__ __launch_bounds__(256) void scatter_edges(
    const int* __restrict__ rows, const int* __restrict__ cols,
    const float* __restrict__ vals, int* __restrict__ pos,
    int2* __restrict__ ep, int E)
{
    int e = blockIdx.x * 256 + threadIdx.x;
    if (e < E) {
        int r = rows[e];
        int p = atomicAdd(&pos[r], 1);
        ep[p] = make_int2(cols[e], __float_as_int(vals[e]));
    }
}

// ============== selMap + needed-row marking =====================
__global__ __launch_bounds__(256) void build_selmap(
    const int* __restrict__ userIdx, const int* __restrict__ itemIdx,
    int* __restrict__ selMap)
{
    int i = blockIdx.x * 256 + threadIdx.x;
    if (i < BATCH) selMap[userIdx[i]] = i;
    else if (i < 2 * BATCH) selMap[itemIdx[i - BATCH]] = i;
}

__global__ __launch_bounds__(256) void mark_needed(
    const int* __restrict__ userIdx, const int* __restrict__ itemIdx,
    const int* __restrict__ ptr_, const int* __restrict__ deg_,
    const int2* __restrict__ ep, int* __restrict__ flag)
{
    int i = blockIdx.x * 4 + ((int)threadIdx.x >> 6);
    if (i >= 2 * BATCH) return;
    int lane = threadIdx.x & 63;
    int row = (i < BATCH) ? userIdx[i] : itemIdx[i - BATCH];
    if (lane == 0) flag[row] = 1;
    int st = ptr_[row], d = deg_[row];
    for (int j = lane; j < d; j += 64)
        flag[ep[st + j].x] = 1;
}

__global__ __launch_bounds__(256) void compact_list(
    const int* __restrict__ flag, const int* __restrict__ fpre,
    const int* __restrict__ bsum, int* __restrict__ list,
    int* __restrict__ count, int n)
{
    int i = blockIdx.x * 256 + threadIdx.x;
    if (i < n) {
        int base = fpre[i] + bsum[i >> 8];
        if (flag[i]) list[base] = i;
        if (i == n - 1) *count = base + flag[i];
    }
}

// ======================= SpMM kernels (bf16 gather) =======================

// Pass 1 (F=100): B1b = bf16(L@X) stride 64 zero-padded; INTb = bf16((L@X).*X) stride 50
__global__ __launch_bounds__(256) void spmm_pass1(
    const int* __restrict__ ptr_, const int* __restrict__ deg_,
    const int2* __restrict__ ep, const uint* __restrict__ Xb,
    uint* __restrict__ B1b, uint* __restrict__ INTb, int N)
{
    int row = blockIdx.x * 4 + ((int)threadIdx.x >> 6);
    if (row >= N) return;
    int lane = threadIdx.x & 63;
    int st = ptr_[row], d = deg_[row];
    float ax = 0.f, ay = 0.f;
    int2 e = (d > 0) ? ep[st] : make_int2(0, 0);
    for (int j = 0; j < d; j++) {
        int c = e.x; float v = __int_as_float(e.y);
        if (j + 1 < d) e = ep[st + j + 1];
        uint bits = Xb[(size_t)c * 64 + lane];     // pad lanes read zeros
        ax = fmaf(v, bf_lo(bits), ax);
        ay = fmaf(v, bf_hi(bits), ay);
    }
    B1b[(size_t)row * 64 + lane] = pack_bf16x2(ax, ay);   // zero in pad lanes
    if (lane < 50) {
        uint xb = Xb[(size_t)row * 64 + lane];
        INTb[(size_t)row * 50 + lane] = pack_bf16x2(ax * bf_lo(xb), ay * bf_hi(xb));
    }
}

// Pass 2 (F=100): B2b = bf16(L @ INTb) stride 64 zero-padded
__global__ __launch_bounds__(256) void spmm_pass2(
    const int* __restrict__ ptr_, const int* __restrict__ deg_,
    const int2* __restrict__ ep, const uint* __restrict__ INTb,
    uint* __restrict__ B2b, int N)
{
    int row = blockIdx.x * 4 + ((int)threadIdx.x >> 6);
    if (row >= N) return;
    int lane = threadIdx.x & 63;
    int st = ptr_[row], d = deg_[row];
    float ax = 0.f, ay = 0.f;
    int2 e = (d > 0) ? ep[st] : make_int2(0, 0);
    for (int j = 0; j < d; j++) {
        int c = e.x; float v = __int_as_float(e.y);
        if (j + 1 < d) e = ep[st + j + 1];
        uint bits = (lane < 50) ? INTb[(size_t)c * 50 + lane] : 0u;
        ax = fmaf(v, bf_lo(bits), ax);
        ay = fmaf(v, bf_hi(bits), ay);
    }
    B2b[(size_t)row * 64 + lane] = pack_bf16x2(ax, ay);
}

// Pass 3 (F=80): fp32 out, only over compacted needed-row list
__global__ __launch_bounds__(256) void spmm_bf_list(
    const int* __restrict__ list, const int* __restrict__ count,
    const int* __restrict__ ptr_, const int* __restrict__ deg_,
    const int2* __restrict__ ep, const uint* __restrict__ F1b,
    float* __restrict__ out)
{
    constexpr int P = 40;
    int idx = blockIdx.x * 4 + ((int)threadIdx.x >> 6);
    if (idx >= *count) return;
    int row = list[idx];
    int lane = threadIdx.x & 63;
    int st = ptr_[row], d = deg_[row];
    float ax = 0.f, ay = 0.f;
    int2 e = (d > 0) ? ep[st] : make_int2(0, 0);
    for (int j = 0; j < d; j++) {
        int c = e.x; float v = __int_as_float(e.y);
        if (j + 1 < d) e = ep[st + j + 1];
        uint bits = (lane < P) ? F1b[(size_t)c * P + lane] : 0u;
        ax = fmaf(v, bf_lo(bits), ax);
        ay = fmaf(v, bf_hi(bits), ay);
    }
    if (lane < P)
        ((float2*)(out + (size_t)row * 80))[lane] = make_float2(ax, ay);
}

// Pass 4 (selected rows): outC[i] = sum_e v * (Lx[c] .* F1[c])
__global__ __launch_bounds__(256) void spmm_sel(
    const int* __restrict__ ptr_, const int* __restrict__ deg_,
    const int2* __restrict__ ep,
    const float* __restrict__ Lx, const uint* __restrict__ F1b,
    const int* __restrict__ userIdx, const int* __restrict__ itemIdx,
    float* __restrict__ outC)
{
    constexpr int P = 40;
    int i = blockIdx.x * 4 + ((int)threadIdx.x >> 6);
    if (i >= 2 * BATCH) return;
    int row = (i < BATCH) ? userIdx[i] : itemIdx[i - BATCH];
    int lane = threadIdx.x & 63;
    int st = ptr_[row], d = deg_[row];
    float ax = 0.f, ay = 0.f;
    int2 e = (d > 0) ? ep[st] : make_int2(0, 0);
    for (int j = 0; j < d; j++) {
        int c = e.x; float v = __int_as_float(e.y);
        if (j + 1 < d) e = ep[st + j + 1];
        float2 l = make_float2(0.f, 0.f);
        uint bits = 0u;
        if (lane < P) {
            l = ((const float2*)(Lx + (size_t)c * 80))[lane];
            bits = F1b[(size_t)c * P + lane];
        }
        ax = fmaf(v, l.x * bf_lo(bits), ax);
        ay = fmaf(v, l.y * bf_hi(bits), ay);
    }
    if (lane < P)
        ((float2*)(outC + (size_t)i * 80))[lane] = make_float2(ax, ay);
}

// ------------- Layer-1 fused linear via MFMA ------------------------------
// F1 = relu(Lx@W + X@W + S2@Wi + b + bi), all A-streams bf16 stride-64-uint.
// Wave: 16 rows x 80 cols. 4 K-steps of 32 per stream (K=100 zero-padded to 128).
__global__ __launch_bounds__(256) void gemm1_mfma(
    const uint* __restrict__ B1b, const uint* __restrict__ Xb,
    const uint* __restrict__ B2b,
    const uint* __restrict__ wtW, const uint* __restrict__ wtWi,
    const float* __restrict__ b, const float* __restrict__ bi,
    const int* __restrict__ selMap,
    ushort_t* __restrict__ F1b, float* __restrict__ F1sel, int N)
{
    int wave = (int)threadIdx.x >> 6;
    int lane = (int)threadIdx.x & 63;
    int rowBase = blockIdx.x * 64 + wave * 16;
    int colLocal = lane & 15;
    int q = lane >> 4;                       // 0..3
    int arow = rowBase + colLocal;           // A-fragment row
    bool rowOK = arow < N;

    f32x4 acc[5];
#pragma unroll
    for (int nt = 0; nt < 5; nt++) acc[nt] = (f32x4){0.f, 0.f, 0.f, 0.f};

    const bf16x8 zfrag = {};
    size_t aoff = (size_t)arow * 64 + q * 4;   // uint index

#pragma unroll
    for (int ks = 0; ks < 4; ks++) {
        bf16x8 aL = rowOK ? *(const bf16x8*)(B1b + aoff + ks * 16) : zfrag;
        bf16x8 aX = rowOK ? *(const bf16x8*)(Xb  + aoff + ks * 16) : zfrag;
        bf16x8 aS = rowOK ? *(const bf16x8*)(B2b + aoff + ks * 16) : zfrag;
#pragma unroll
        for (int nt = 0; nt < 5; nt++) {
            size_t boff = (size_t)(nt * 16 + colLocal) * 64 + ks * 16 + q * 4;
            bf16x8 bW  = *(const bf16x8*)(wtW  + boff);
            bf16x8 bWi = *(const bf16x8*)(wtWi + boff);
            acc[nt] = __builtin_amdgcn_mfma_f32_16x16x32_bf16(aL, bW,  acc[nt], 0, 0, 0);
            acc[nt] = __builtin_amdgcn_mfma_f32_16x16x32_bf16(aX, bW,  acc[nt], 0, 0, 0);
            acc[nt] = __builtin_amdgcn_mfma_f32_16x16x32_bf16(aS, bWi, acc[nt], 0, 0, 0);
        }
    }

    // Epilogue. D layout: col = lane&15 (N-dim), row = q*4 + reg (M-dim).
    int sm[4];
    bool rok[4];
#pragma unroll
    for (int reg = 0; reg < 4; reg++) {
        int row = rowBase + q * 4 + reg;
        rok[reg] = row < N;
        sm[reg] = rok[reg] ? selMap[row] : -1;
    }
#pragma unroll
    for (int nt = 0; nt < 5; nt++) {
        int col = nt * 16 + colLocal;
        float bias = b[col] + bi[col];
#pragma unroll
        for (int reg = 0; reg < 4; reg++) {
            if (!rok[reg]) continue;
            int row = rowBase + q * 4 + reg;
            float v = fmaxf(acc[nt][reg] + bias, 0.f);
            F1b[(size_t)row * 80 + col] = cvt_bf16(v);
            if (sm[reg] >= 0) F1sel[(size_t)sm[reg] * 80 + col] = v;
        }
    }
}

// Layer-2 fused GEMM restricted to sampled rows; X via compact F1sel.
__global__ __launch_bounds__(256) void gemm_fused2_sel(
    const float* __restrict__ Lx, const float* __restrict__ F1sel,
    const int* __restrict__ selMap,
    const float* __restrict__ S2c,
    const float* __restrict__ W, const float* __restrict__ b,
    const float* __restrict__ Wi, const float* __restrict__ bi,
    const int* __restrict__ userIdx, const int* __restrict__ itemIdx,
    float* __restrict__ outC)
{
    constexpr int K = 80, M = 50, TPR = 2, MT = M / TPR;
    __shared__ float sW[K * M];
    __shared__ float sWi[K * M];
    for (int i = threadIdx.x; i < K * M; i += 256) {
        sW[i]  = W[i];
        sWi[i] = Wi[i];
    }
    __syncthreads();

    int i = blockIdx.x * (256 / TPR) + (int)threadIdx.x / TPR;
    int mBase = ((int)threadIdx.x % TPR) * MT;
    if (i >= 2 * BATCH) return;
    int r = (i < BATCH) ? userIdx[i] : itemIdx[i - BATCH];

    const float* xrow = F1sel + (size_t)selMap[r] * K;
    const float* lrow = Lx + (size_t)r * K;
    const float* srow = S2c + (size_t)i * K;

    float acc[MT];
#pragma unroll
    for (int m = 0; m < MT; m++) acc[m] = 0.0f;

    for (int k4 = 0; k4 < K; k4 += 4) {
        float4 lv = *(const float4*)(lrow + k4);
        float4 xv = *(const float4*)(xrow + k4);
        float4 sv = *(const float4*)(srow + k4);
        float a[4] = {lv.x + xv.x, lv.y + xv.y, lv.z + xv.z, lv.w + xv.w};
        float s[4] = {sv.x, sv.y, sv.z, sv.w};
#pragma unroll
        for (int kk = 0; kk < 4; kk++) {
            const float* wk  = &sW[(k4 + kk) * M + mBase];
            const float* wik = &sWi[(k4 + kk) * M + mBase];
#pragma unroll
            for (int m = 0; m < MT; m++)
                acc[m] = fmaf(a[kk], wk[m], fmaf(s[kk], wik[m], acc[m]));
        }
    }

    float* orow = outC + (size_t)i * M + mBase;
#pragma unroll
    for (int m = 0; m < MT; m++)
        orow[m] = fmaxf(acc[m] + b[mBase + m] + bi[mBase + m], 0.0f);
}

// ------------- Plain MLP GEMM ---------------------------------------------
template<int K, int M, int TPR, bool RELU>
__global__ __launch_bounds__(256) void mlp_gemm(
    const float* __restrict__ A,
    const float* __restrict__ W, const float* __restrict__ b,
    float* __restrict__ out, int N)
{
    __shared__ float sW[K * M];
    for (int i = threadIdx.x; i < K * M; i += 256) sW[i] = W[i];
    __syncthreads();

    constexpr int RPB = 256 / TPR;
    constexpr int MT  = M / TPR;
    int r = blockIdx.x * RPB + (int)threadIdx.x / TPR;
    int mBase = ((int)threadIdx.x % TPR) * MT;
    if (r >= N) return;

    const float* arow = A + (size_t)r * K;
    float acc[MT];
#pragma unroll
    for (int m = 0; m < MT; m++) acc[m] = 0.0f;

    for (int k = 0; k < K; k++) {
        float a = arow[k];
#pragma unroll
        for (int m = 0; m < MT; m++)
            acc[m] = fmaf(a, sW[k * M + mBase + m], acc[m]);
    }

    float* orow = out + (size_t)r * M + mBase;
#pragma unroll
    for (int m = 0; m < MT; m++) {
        float vv = acc[m] + b[mBase + m];
        orow[m] = RELU ? fmaxf(vv, 0.0f) : vv;
    }
}

// ------------- Gather final embeddings into [BATCH, 460] ------------------
__global__ __launch_bounds__(128) void gather_embd(
    const int* __restrict__ userIdx, const int* __restrict__ itemIdx,
    const float* __restrict__ uE, const float* __restrict__ iE,
    const float* __restrict__ F1sel, const int* __restrict__ selMap,
    const float* __restrict__ f2c,
    float* __restrict__ emb)
{
    int bi = blockIdx.x;
    int u  = userIdx[bi];
    int it = itemIdx[bi];
    int su = selMap[u];
    int si = selMap[it];
    float* orow = emb + (size_t)bi * 460;
    for (int c = threadIdx.x; c < 460; c += 128) {
        float val;
        if (c < 100) {
            val = (u < N_USERS) ? uE[(size_t)u * 100 + c]
                                : iE[(size_t)(u - N_USERS) * 100 + c];
        } else if (c < 180) {
            val = F1sel[(size_t)su * 80 + (c - 100)];
        } else if (c < 230) {
            val = f2c[(size_t)bi * 50 + (c - 180)];
        } else if (c < 330) {
            int cc = c - 230;
            val = (it < N_USERS) ? uE[(size_t)it * 100 + cc]
                                 : iE[(size_t)(it - N_USERS) * 100 + cc];
        } else if (c < 410) {
            val = F1sel[(size_t)si * 80 + (c - 330)];
        } else {
            val = f2c[(size_t)(BATCH + bi) * 50 + (c - 410)];
        }
        orow[c] = val;
    }
}

extern "C" void kernel_launch(void* const* d_in, const int* in_sizes, int n_in,
                              void* d_out, int out_size, void* d_ws, size_t ws_size,
                              hipStream_t stream) {
    const int*   userIdx = (const int*)d_in[0];
    const int*   itemIdx = (const int*)d_in[1];
    const int*   rows    = (const int*)d_in[2];
    const int*   cols    = (const int*)d_in[3];
    const float* vals    = (const float*)d_in[4];
    const float* uEmbd   = (const float*)d_in[5];
    const float* iEmbd   = (const float*)d_in[6];
    const float* w1      = (const float*)d_in[7];
    const float* b1      = (const float*)d_in[8];
    const float* wi1     = (const float*)d_in[9];
    const float* bi1     = (const float*)d_in[10];
    const float* w2      = (const float*)d_in[11];
    const float* b2      = (const float*)d_in[12];
    const float* wi2     = (const float*)d_in[13];
    const float* bi2     = (const float*)d_in[14];
    const float* t1w     = (const float*)d_in[15];
    const float* t1b     = (const float*)d_in[16];
    const float* t2w     = (const float*)d_in[17];
    const float* t2b     = (const float*)d_in[18];
    const float* t3w     = (const float*)d_in[19];
    const float* t3b     = (const float*)d_in[20];

    // ---- workspace layout (4-byte units) ----
    float* ws = (float*)d_ws;
    uint*  Xb    = (uint*)ws;                  //  9,600,000  (150K x 64, padded)
    uint*  B1b   = (uint*)(ws + 9600000);      //  9,600,000  (padded)
    uint*  INTb  = (uint*)(ws + 19200000);     //  7,500,000  (stride 50)
    uint*  B2b   = (uint*)(ws + 26700000);     //  9,600,000  (padded)
    uint*  F1b   = (uint*)(ws + 36300000);     //  6,000,000  (stride 40)
    uint*  wtW   = (uint*)(ws + 42300000);     //      5,120
    uint*  wtWi  = (uint*)(ws + 42305120);     //      5,120
    float* F1sel = ws + 42310240;              //    655,360
    float* B2c   = ws + 42965600;              //    655,360
    float* F2c   = ws + 43620960;              //    409,600
    float* EMB   = ws + 44030560;              //  1,884,160
    float* H1    = ws + 45914720;              //    262,144
    float* H2    = ws + 46176864;              //    131,072
    int*   deg   = (int*)(ws + 46307936);      //    150,000
    int*   ptr   = deg + 150000;
    int*   pos   = ptr + 150000;
    int*   bsum  = pos + 150000;               //      1,024
    int2*  ep    = (int2*)(bsum + 1024);       //  1,500,000 int2
    int*   flag  = (int*)(ep + 1500000);       //    150,000
    int*   fpre  = flag + 150000;
    int*   list  = fpre + 150000;
    int*   bsum2 = list + 150000;              //      1,024
    int*   cnt   = bsum2 + 1024;
    int*   selMap= cnt + 1;                    //    150,000  (~201.5 MB total)
    // Layer-2 Lx (fp32, 150K x 80 = 12M floats) aliases B1b+INTb (dead after gemm1)
    float* B1f   = ws + 9600000;

    const int E = N_EDGES;
    dim3 blk(256);

    // ---- prep: bf16 features + transposed bf16 weights ----
    cast_feats<<<(N_NODES * 64 + 255) / 256, blk, 0, stream>>>(uEmbd, iEmbd, Xb);
    prep_weights<<<(2 * 80 * 64 + 255) / 256, blk, 0, stream>>>(w1, wi1, wtW, wtWi);

    // ---- CSR build ----
    hipMemsetAsync(deg, 0, 150000 * sizeof(int), stream);
    hipMemsetAsync(flag, 0, 150000 * sizeof(int), stream);
    hipMemsetAsync(selMap, 0xFF, 150000 * sizeof(int), stream);
    hist_kernel<<<(E + 255) / 256, blk, 0, stream>>>(rows, deg, E);
    int nScanBlocks = (N_NODES + 255) / 256;            // 586
    scan_block<<<nScanBlocks, blk, 0, stream>>>(deg, ptr, bsum, N_NODES);
    scan_tops<<<1, dim3(1024), 0, stream>>>(bsum, nScanBlocks);
    scan_apply<<<nScanBlocks, blk, 0, stream>>>(ptr, bsum, pos, N_NODES);
    scatter_edges<<<(E + 255) / 256, blk, 0, stream>>>(rows, cols, vals, pos, ep, E);

    // ---- selMap + needed-row marking + compaction ----
    build_selmap<<<(2 * BATCH + 255) / 256, blk, 0, stream>>>(userIdx, itemIdx, selMap);
    mark_needed<<<(2 * BATCH + 3) / 4, blk, 0, stream>>>(
        userIdx, itemIdx, ptr, deg, ep, flag);
    scan_block<<<nScanBlocks, blk, 0, stream>>>(flag, fpre, bsum2, N_NODES);
    scan_tops<<<1, dim3(1024), 0, stream>>>(bsum2, nScanBlocks);
    compact_list<<<nScanBlocks, blk, 0, stream>>>(flag, fpre, bsum2, list, cnt, N_NODES);

    int rowGrid = (N_NODES + 3) / 4;
    int selGrid = (2 * BATCH + 3) / 4;

    // ---- Layer 1 (F = 100) ----
    spmm_pass1<<<rowGrid, blk, 0, stream>>>(ptr, deg, ep, Xb, B1b, INTb, N_NODES);
    spmm_pass2<<<rowGrid, blk, 0, stream>>>(ptr, deg, ep, INTb, B2b, N_NODES);
    {
        int grid = (N_NODES + 63) / 64;       // 64 rows / block (4 waves x 16)
        gemm1_mfma<<<grid, blk, 0, stream>>>(
            B1b, Xb, B2b, wtW, wtWi, b1, bi1, selMap,
            (ushort_t*)F1b, F1sel, N_NODES);
    }

    // ---- Layer 2 (F = 80) ----
    spmm_bf_list<<<rowGrid, blk, 0, stream>>>(
        list, cnt, ptr, deg, ep, F1b, B1f);
    spmm_sel<<<selGrid, blk, 0, stream>>>(
        ptr, deg, ep, B1f, F1b, userIdx, itemIdx, B2c);
    {
        int grid = (2 * BATCH + 127) / 128;
        gemm_fused2_sel<<<grid, blk, 0, stream>>>(
            B1f, F1sel, selMap, B2c, w2, b2, wi2, bi2, userIdx, itemIdx, F2c);
    }

    // ---- Gather + MLP ----
    gather_embd<<<BATCH, dim3(128), 0, stream>>>(
        userIdx, itemIdx, uEmbd, iEmbd, F1sel, selMap, F2c, EMB);
    {
        constexpr int TPR = 8;
        int grid = (BATCH + (256 / TPR) - 1) / (256 / TPR);
        mlp_gemm<460, 64, TPR, true><<<grid, blk, 0, stream>>>(
            EMB, t1w, t1b, H1, BATCH);
    }
    {
        constexpr int TPR = 4;
        int grid = (BATCH + (256 / TPR) - 1) / (256 / TPR);
        mlp_gemm<64, 32, TPR, false><<<grid, blk, 0, stream>>>(
            H1, t2w, t2b, H2, BATCH);
    }
    {
        constexpr int TPR = 1;
        int grid = (BATCH + 255) / 256;
        mlp_gemm<32, 1, TPR, false><<<grid, blk, 0, stream>>>(
            H2, t3w, t3b, (float*)d_out, BATCH);
    }
}

// Round 7
// 613.781 us; speedup vs baseline: 1.3190x; 1.0771x over previous
//
#include <hip/hip_runtime.h>

typedef unsigned int uint;
typedef unsigned short ushort_t;
typedef __attribute__((ext_vector_type(4))) float f32x4;
typedef __attribute__((ext_vector_type(8))) short bf16x8;

#define N_USERS 100000
#define N_ITEMS 50000
#define N_NODES 150000
#define N_EDGES 1500000
#define BATCH 4096

__device__ __forceinline__ uint pack_bf16x2(float a, float b) {
    uint ua = __float_as_uint(a);
    uint ub = __float_as_uint(b);
    ua = (ua + 0x7FFFu + ((ua >> 16) & 1u)) >> 16;
    ub = (ub + 0x7FFFu + ((ub >> 16) & 1u)) >> 16;
    return ua | (ub << 16);
}
__device__ __forceinline__ ushort_t cvt_bf16(float a) {
    uint ua = __float_as_uint(a);
    return (ushort_t)((ua + 0x7FFFu + ((ua >> 16) & 1u)) >> 16);
}
__device__ __forceinline__ float bf_lo(uint u) { return __uint_as_float(u << 16); }
__device__ __forceinline__ float bf_hi(uint u) { return __uint_as_float(u & 0xFFFF0000u); }

// ===== 4-deep pipelined row gather-accumulate: sum_e v_e * src[col_e][lane] ====
// ep must be padded by >=8 entries past the last edge (addresses prefetched
// unguarded; gathers & FMAs are guarded by j<d).
template<int P>
__device__ __forceinline__ float2 row_gather_accum(
    const int2* __restrict__ ep, int st, int d,
    const uint* __restrict__ src, int lane)
{
    float ax = 0.f, ay = 0.f;
    bool lok = lane < P;
    int2 e0 = ep[st],     e1 = ep[st + 1], e2 = ep[st + 2], e3 = ep[st + 3];
    int2 e4 = ep[st + 4], e5 = ep[st + 5];
    uint b0 = (lok && 0 < d) ? src[(size_t)e0.x * P + lane] : 0u;
    uint b1 = (lok && 1 < d) ? src[(size_t)e1.x * P + lane] : 0u;
    uint b2 = (lok && 2 < d) ? src[(size_t)e2.x * P + lane] : 0u;
    uint b3 = (lok && 3 < d) ? src[(size_t)e3.x * P + lane] : 0u;
    for (int j = 0; j < d; j += 2) {
        uint n4 = (lok && j + 4 < d) ? src[(size_t)e4.x * P + lane] : 0u;
        uint n5 = (lok && j + 5 < d) ? src[(size_t)e5.x * P + lane] : 0u;
        int2 n6 = ep[st + j + 6];
        int2 n7 = ep[st + j + 7];
        float v0 = __int_as_float(e0.y);
        ax = fmaf(v0, bf_lo(b0), ax);
        ay = fmaf(v0, bf_hi(b0), ay);
        if (j + 1 < d) {
            float v1 = __int_as_float(e1.y);
            ax = fmaf(v1, bf_lo(b1), ax);
            ay = fmaf(v1, bf_hi(b1), ay);
        }
        e0 = e2; b0 = b2; e1 = e3; b1 = b3;
        e2 = e4; b2 = n4; e3 = e5; b3 = n5;
        e4 = n6; e5 = n7;
    }
    return make_float2(ax, ay);
}

// Dual-stream variant: sum_e v_e * (A[col_e][lane] .* B[col_e][lane]), P=40
__device__ __forceinline__ float2 row_gather_accum_mul(
    const int2* __restrict__ ep, int st, int d,
    const uint* __restrict__ sA, const uint* __restrict__ sB, int lane)
{
    constexpr int P = 40;
    float ax = 0.f, ay = 0.f;
    bool lok = lane < P;
    int2 e0 = ep[st],     e1 = ep[st + 1], e2 = ep[st + 2], e3 = ep[st + 3];
    int2 e4 = ep[st + 4], e5 = ep[st + 5];
    uint a0 = (lok && 0 < d) ? sA[(size_t)e0.x * P + lane] : 0u;
    uint c0 = (lok && 0 < d) ? sB[(size_t)e0.x * P + lane] : 0u;
    uint a1 = (lok && 1 < d) ? sA[(size_t)e1.x * P + lane] : 0u;
    uint c1 = (lok && 1 < d) ? sB[(size_t)e1.x * P + lane] : 0u;
    uint a2 = (lok && 2 < d) ? sA[(size_t)e2.x * P + lane] : 0u;
    uint c2 = (lok && 2 < d) ? sB[(size_t)e2.x * P + lane] : 0u;
    uint a3 = (lok && 3 < d) ? sA[(size_t)e3.x * P + lane] : 0u;
    uint c3 = (lok && 3 < d) ? sB[(size_t)e3.x * P + lane] : 0u;
    for (int j = 0; j < d; j += 2) {
        uint nA4 = (lok && j + 4 < d) ? sA[(size_t)e4.x * P + lane] : 0u;
        uint nC4 = (lok && j + 4 < d) ? sB[(size_t)e4.x * P + lane] : 0u;
        uint nA5 = (lok && j + 5 < d) ? sA[(size_t)e5.x * P + lane] : 0u;
        uint nC5 = (lok && j + 5 < d) ? sB[(size_t)e5.x * P + lane] : 0u;
        int2 n6 = ep[st + j + 6];
        int2 n7 = ep[st + j + 7];
        float v0 = __int_as_float(e0.y);
        ax = fmaf(v0, bf_lo(a0) * bf_lo(c0), ax);
        ay = fmaf(v0, bf_hi(a0) * bf_hi(c0), ay);
        if (j + 1 < d) {
            float v1 = __int_as_float(e1.y);
            ax = fmaf(v1, bf_lo(a1) * bf_lo(c1), ax);
            ay = fmaf(v1, bf_hi(a1) * bf_hi(c1), ay);
        }
        e0 = e2; a0 = a2; c0 = c2; e1 = e3; a1 = a3; c1 = c3;
        e2 = e4; a2 = nA4; c2 = nC4; e3 = e5; a3 = nA5; c3 = nC5;
        e4 = n6; e5 = n7;
    }
    return make_float2(ax, ay);
}

// ============ bf16 feature cast: padded (stride 64) + compact (stride 50) =====
__global__ __launch_bounds__(256) void cast_feats(
    const float* __restrict__ uE, const float* __restrict__ iE,
    uint* __restrict__ Xb64, uint* __restrict__ Xc50)
{
    int g = blockIdx.x * 256 + threadIdx.x;
    if (g >= N_NODES * 64) return;
    int row = g >> 6, c = g & 63;
    uint outv = 0u;
    if (c < 50) {
        int e0 = c * 2;
        float a, b;
        if (row < N_USERS) { a = uE[(size_t)row * 100 + e0]; b = uE[(size_t)row * 100 + e0 + 1]; }
        else { a = iE[(size_t)(row - N_USERS) * 100 + e0]; b = iE[(size_t)(row - N_USERS) * 100 + e0 + 1]; }
        outv = pack_bf16x2(a, b);
        Xc50[(size_t)row * 50 + c] = outv;
    }
    Xb64[g] = outv;
}

// ============ weight prep: wT bf16 [80 cols][64 uints=128 k, zero-padded] =====
__global__ __launch_bounds__(256) void prep_weights(
    const float* __restrict__ W, const float* __restrict__ Wi,
    uint* __restrict__ wtW, uint* __restrict__ wtWi)
{
    int t = blockIdx.x * 256 + threadIdx.x;
    if (t >= 2 * 80 * 64) return;
    const float* src = (t < 80 * 64) ? W : Wi;
    uint* dst = (t < 80 * 64) ? wtW : wtWi;
    int i = t % (80 * 64);
    int col = i >> 6, kk = i & 63;
    int k = kk * 2;
    uint v = 0u;
    if (k < 100) v = pack_bf16x2(src[(size_t)k * 80 + col], src[(size_t)(k + 1) * 80 + col]);
    dst[(size_t)col * 64 + kk] = v;
}

// ======================= CSR construction =======================
__global__ __launch_bounds__(256) void hist_kernel(
    const int* __restrict__ rows, int* __restrict__ deg, int E)
{
    int e = blockIdx.x * 256 + threadIdx.x;
    if (e < E) atomicAdd(&deg[rows[e]], 1);
}

__global__ __launch_bounds__(256) void scan_block(
    const int* __restrict__ deg, int* __restrict__ ptr,
    int* __restrict__ bsum, int n)
{
    __shared__ int s[256];
    int t = threadIdx.x;
    int i = blockIdx.x * 256 + t;
    int v = (i < n) ? deg[i] : 0;
    s[t] = v; __syncthreads();
    for (int off = 1; off < 256; off <<= 1) {
        int x = (t >= off) ? s[t - off] : 0;
        __syncthreads();
        s[t] += x;
        __syncthreads();
    }
    if (i < n) ptr[i] = s[t] - v;
    if (t == 255) bsum[blockIdx.x] = s[255];
}

__global__ __launch_bounds__(1024) void scan_tops(int* __restrict__ bsum, int nb)
{
    __shared__ int s[1024];
    int t = threadIdx.x;
    int v = (t < nb) ? bsum[t] : 0;
    s[t] = v; __syncthreads();
    for (int off = 1; off < 1024; off <<= 1) {
        int x = (t >= off) ? s[t - off] : 0;
        __syncthreads();
        s[t] += x;
        __syncthreads();
    }
    if (t < nb) bsum[t] = s[t] - v;
}

__global__ __launch_bounds__(256) void scan_apply(
    int* __restrict__ ptr, const int* __restrict__ bsum,
    int* __restrict__ pos, int n)
{
    int i = blockIdx.x * 256 + threadIdx.x;
    if (i < n) {
        int p = ptr[i] + bsum[i >> 8];
        ptr[i] = p;
        pos[i] = p;
    }
}

__global__ __launch_bounds__(256) void scatter_edges(
    const int* __restrict__ rows, const int* __restrict__ cols,
    const float* __restrict__ vals, int* __restrict__ pos,
    int2* __restrict__ ep, int E)
{
    int e = blockIdx.x * 256 + threadIdx.x;
    if (e < E) {
        int r = rows[e];
        int p = atomicAdd(&pos[r], 1);
        ep[p] = make_int2(cols[e], __float_as_int(vals[e]));
    }
}

// ============== selMap + needed-row marking =====================
__global__ __launch_bounds__(256) void build_selmap(
    const int* __restrict__ userIdx, const int* __restrict__ itemIdx,
    int* __restrict__ selMap)
{
    int i = blockIdx.x * 256 + threadIdx.x;
    if (i < BATCH) selMap[userIdx[i]] = i;
    else if (i < 2 * BATCH) selMap[itemIdx[i - BATCH]] = i;
}

__global__ __launch_bounds__(256) void mark_needed(
    const int* __restrict__ userIdx, const int* __restrict__ itemIdx,
    const int* __restrict__ ptr_, const int* __restrict__ deg_,
    const int2* __restrict__ ep, int* __restrict__ flag)
{
    int i = blockIdx.x * 4 + ((int)threadIdx.x >> 6);
    if (i >= 2 * BATCH) return;
    int lane = threadIdx.x & 63;
    int row = (i < BATCH) ? userIdx[i] : itemIdx[i - BATCH];
    if (lane == 0) flag[row] = 1;
    int st = ptr_[row], d = deg_[row];
    for (int j = lane; j < d; j += 64)
        flag[ep[st + j].x] = 1;
}

__global__ __launch_bounds__(256) void compact_list(
    const int* __restrict__ flag, const int* __restrict__ fpre,
    const int* __restrict__ bsum, int* __restrict__ list,
    int* __restrict__ count, int n)
{
    int i = blockIdx.x * 256 + threadIdx.x;
    if (i < n) {
        int base = fpre[i] + bsum[i >> 8];
        if (flag[i]) list[base] = i;
        if (i == n - 1) *count = base + flag[i];
    }
}

// ======================= SpMM kernels (bf16 gather, pipelined) =================

// Pass 1 (F=100): B1b64 = bf16(L@X) padded; INTb50 = bf16((L@X) .* X)
__global__ __launch_bounds__(256) void spmm_pass1(
    const int* __restrict__ ptr_, const int* __restrict__ deg_,
    const int2* __restrict__ ep, const uint* __restrict__ Xc,
    uint* __restrict__ B1b, uint* __restrict__ INTb, int N)
{
    int row = blockIdx.x * 4 + ((int)threadIdx.x >> 6);
    if (row >= N) return;
    int lane = threadIdx.x & 63;
    float2 r = row_gather_accum<50>(ep, ptr_[row], deg_[row], Xc, lane);
    B1b[(size_t)row * 64 + lane] = pack_bf16x2(r.x, r.y);   // pad lanes pack 0
    if (lane < 50) {
        uint xb = Xc[(size_t)row * 50 + lane];
        INTb[(size_t)row * 50 + lane] = pack_bf16x2(r.x * bf_lo(xb), r.y * bf_hi(xb));
    }
}

// Pass 2 (F=100): B2b64 = bf16(L @ INTb) padded
__global__ __launch_bounds__(256) void spmm_pass2(
    const int* __restrict__ ptr_, const int* __restrict__ deg_,
    const int2* __restrict__ ep, const uint* __restrict__ INTb,
    uint* __restrict__ B2b, int N)
{
    int row = blockIdx.x * 4 + ((int)threadIdx.x >> 6);
    if (row >= N) return;
    int lane = threadIdx.x & 63;
    float2 r = row_gather_accum<50>(ep, ptr_[row], deg_[row], INTb, lane);
    B2b[(size_t)row * 64 + lane] = pack_bf16x2(r.x, r.y);
}

// Pass 3 (F=80): Lx2 = L@F1 over needed list; writes bf16 Lxb40 + fp32 Lxsel
__global__ __launch_bounds__(256) void spmm_pass3(
    const int* __restrict__ list, const int* __restrict__ count,
    const int* __restrict__ ptr_, const int* __restrict__ deg_,
    const int2* __restrict__ ep, const uint* __restrict__ F1b,
    const int* __restrict__ selMap,
    uint* __restrict__ Lxb, float* __restrict__ Lxsel)
{
    int idx = blockIdx.x * 4 + ((int)threadIdx.x >> 6);
    if (idx >= *count) return;
    int row = list[idx];
    int lane = threadIdx.x & 63;
    float2 r = row_gather_accum<40>(ep, ptr_[row], deg_[row], F1b, lane);
    if (lane < 40) {
        Lxb[(size_t)row * 40 + lane] = pack_bf16x2(r.x, r.y);
        int sm = selMap[row];
        if (sm >= 0)
            ((float2*)(Lxsel + (size_t)sm * 80))[lane] = r;
    }
}

// Pass 4 (selected rows): B2c[i] = sum_e v * (Lx2[c] .* F1[c]), both bf16
__global__ __launch_bounds__(256) void spmm_pass4(
    const int* __restrict__ ptr_, const int* __restrict__ deg_,
    const int2* __restrict__ ep,
    const uint* __restrict__ Lxb, const uint* __restrict__ F1b,
    const int* __restrict__ userIdx, const int* __restrict__ itemIdx,
    float* __restrict__ outC)
{
    int i = blockIdx.x * 4 + ((int)threadIdx.x >> 6);
    if (i >= 2 * BATCH) return;
    int row = (i < BATCH) ? userIdx[i] : itemIdx[i - BATCH];
    int lane = threadIdx.x & 63;
    float2 r = row_gather_accum_mul(ep, ptr_[row], deg_[row], Lxb, F1b, lane);
    if (lane < 40)
        ((float2*)(outC + (size_t)i * 80))[lane] = r;
}

// ------------- Layer-1 fused linear via MFMA ------------------------------
__global__ __launch_bounds__(256) void gemm1_mfma(
    const uint* __restrict__ B1b, const uint* __restrict__ Xb,
    const uint* __restrict__ B2b,
    const uint* __restrict__ wtW, const uint* __restrict__ wtWi,
    const float* __restrict__ b, const float* __restrict__ bi,
    const int* __restrict__ selMap,
    ushort_t* __restrict__ F1b, float* __restrict__ F1sel, int N)
{
    int wave = (int)threadIdx.x >> 6;
    int lane = (int)threadIdx.x & 63;
    int rowBase = blockIdx.x * 64 + wave * 16;
    int colLocal = lane & 15;
    int q = lane >> 4;
    int arow = rowBase + colLocal;
    bool rowOK = arow < N;

    f32x4 acc[5];
#pragma unroll
    for (int nt = 0; nt < 5; nt++) acc[nt] = (f32x4){0.f, 0.f, 0.f, 0.f};

    const bf16x8 zfrag = {};
    size_t aoff = (size_t)arow * 64 + q * 4;

#pragma unroll
    for (int ks = 0; ks < 4; ks++) {
        bf16x8 aL = rowOK ? *(const bf16x8*)(B1b + aoff + ks * 16) : zfrag;
        bf16x8 aX = rowOK ? *(const bf16x8*)(Xb  + aoff + ks * 16) : zfrag;
        bf16x8 aS = rowOK ? *(const bf16x8*)(B2b + aoff + ks * 16) : zfrag;
#pragma unroll
        for (int nt = 0; nt < 5; nt++) {
            size_t boff = (size_t)(nt * 16 + colLocal) * 64 + ks * 16 + q * 4;
            bf16x8 bW  = *(const bf16x8*)(wtW  + boff);
            bf16x8 bWi = *(const bf16x8*)(wtWi + boff);
            acc[nt] = __builtin_amdgcn_mfma_f32_16x16x32_bf16(aL, bW,  acc[nt], 0, 0, 0);
            acc[nt] = __builtin_amdgcn_mfma_f32_16x16x32_bf16(aX, bW,  acc[nt], 0, 0, 0);
            acc[nt] = __builtin_amdgcn_mfma_f32_16x16x32_bf16(aS, bWi, acc[nt], 0, 0, 0);
        }
    }

    int sm[4];
    bool rok[4];
#pragma unroll
    for (int reg = 0; reg < 4; reg++) {
        int row = rowBase + q * 4 + reg;
        rok[reg] = row < N;
        sm[reg] = rok[reg] ? selMap[row] : -1;
    }
#pragma unroll
    for (int nt = 0; nt < 5; nt++) {
        int col = nt * 16 + colLocal;
        float bias = b[col] + bi[col];
#pragma unroll
        for (int reg = 0; reg < 4; reg++) {
            if (!rok[reg]) continue;
            int row = rowBase + q * 4 + reg;
            float v = fmaxf(acc[nt][reg] + bias, 0.f);
            F1b[(size_t)row * 80 + col] = cvt_bf16(v);
            if (sm[reg] >= 0) F1sel[(size_t)sm[reg] * 80 + col] = v;
        }
    }
}

// Layer-2 fused GEMM restricted to sampled rows; Lx and X via compact buffers.
__global__ __launch_bounds__(256) void gemm_fused2_sel(
    const float* __restrict__ Lxsel, const float* __restrict__ F1sel,
    const int* __restrict__ selMap,
    const float* __restrict__ S2c,
    const float* __restrict__ W, const float* __restrict__ b,
    const float* __restrict__ Wi, const float* __restrict__ bi,
    const int* __restrict__ userIdx, const int* __restrict__ itemIdx,
    float* __restrict__ outC)
{
    constexpr int K = 80, M = 50, TPR = 2, MT = M / TPR;
    __shared__ float sW[K * M];
    __shared__ float sWi[K * M];
    for (int i = threadIdx.x; i < K * M; i += 256) {
        sW[i]  = W[i];
        sWi[i] = Wi[i];
    }
    __syncthreads();

    int i = blockIdx.x * (256 / TPR) + (int)threadIdx.x / TPR;
    int mBase = ((int)threadIdx.x % TPR) * MT;
    if (i >= 2 * BATCH) return;
    int r = (i < BATCH) ? userIdx[i] : itemIdx[i - BATCH];
    int sm = selMap[r];

    const float* xrow = F1sel + (size_t)sm * K;
    const float* lrow = Lxsel + (size_t)sm * K;
    const float* srow = S2c + (size_t)i * K;

    float acc[MT];
#pragma unroll
    for (int m = 0; m < MT; m++) acc[m] = 0.0f;

    for (int k4 = 0; k4 < K; k4 += 4) {
        float4 lv = *(const float4*)(lrow + k4);
        float4 xv = *(const float4*)(xrow + k4);
        float4 sv = *(const float4*)(srow + k4);
        float a[4] = {lv.x + xv.x, lv.y + xv.y, lv.z + xv.z, lv.w + xv.w};
        float s[4] = {sv.x, sv.y, sv.z, sv.w};
#pragma unroll
        for (int kk = 0; kk < 4; kk++) {
            const float* wk  = &sW[(k4 + kk) * M + mBase];
            const float* wik = &sWi[(k4 + kk) * M + mBase];
#pragma unroll
            for (int m = 0; m < MT; m++)
                acc[m] = fmaf(a[kk], wk[m], fmaf(s[kk], wik[m], acc[m]));
        }
    }

    float* orow = outC + (size_t)i * M + mBase;
#pragma unroll
    for (int m = 0; m < MT; m++)
        orow[m] = fmaxf(acc[m] + b[mBase + m] + bi[mBase + m], 0.0f);
}

// ------------- Plain MLP GEMM ---------------------------------------------
template<int K, int M, int TPR, bool RELU>
__global__ __launch_bounds__(256) void mlp_gemm(
    const float* __restrict__ A,
    const float* __restrict__ W, const float* __restrict__ b,
    float* __restrict__ out, int N)
{
    __shared__ float sW[K * M];
    for (int i = threadIdx.x; i < K * M; i += 256) sW[i] = W[i];
    __syncthreads();

    constexpr int RPB = 256 / TPR;
    constexpr int MT  = M / TPR;
    int r = blockIdx.x * RPB + (int)threadIdx.x / TPR;
    int mBase = ((int)threadIdx.x % TPR) * MT;
    if (r >= N) return;

    const float* arow = A + (size_t)r * K;
    float acc[MT];
#pragma unroll
    for (int m = 0; m < MT; m++) acc[m] = 0.0f;

    for (int k = 0; k < K; k++) {
        float a = arow[k];
#pragma unroll
        for (int m = 0; m < MT; m++)
            acc[m] = fmaf(a, sW[k * M + mBase + m], acc[m]);
    }

    float* orow = out + (size_t)r * M + mBase;
#pragma unroll
    for (int m = 0; m < MT; m++) {
        float vv = acc[m] + b[mBase + m];
        orow[m] = RELU ? fmaxf(vv, 0.0f) : vv;
    }
}

// ------------- Gather final embeddings into [BATCH, 460] ------------------
__global__ __launch_bounds__(128) void gather_embd(
    const int* __restrict__ userIdx, const int* __restrict__ itemIdx,
    const float* __restrict__ uE, const float* __restrict__ iE,
    const float* __restrict__ F1sel, const int* __restrict__ selMap,
    const float* __restrict__ f2c,
    float* __restrict__ emb)
{
    int bi = blockIdx.x;
    int u  = userIdx[bi];
    int it = itemIdx[bi];
    int su = selMap[u];
    int si = selMap[it];
    float* orow = emb + (size_t)bi * 460;
    for (int c = threadIdx.x; c < 460; c += 128) {
        float val;
        if (c < 100) {
            val = (u < N_USERS) ? uE[(size_t)u * 100 + c]
                                : iE[(size_t)(u - N_USERS) * 100 + c];
        } else if (c < 180) {
            val = F1sel[(size_t)su * 80 + (c - 100)];
        } else if (c < 230) {
            val = f2c[(size_t)bi * 50 + (c - 180)];
        } else if (c < 330) {
            int cc = c - 230;
            val = (it < N_USERS) ? uE[(size_t)it * 100 + cc]
                                 : iE[(size_t)(it - N_USERS) * 100 + cc];
        } else if (c < 410) {
            val = F1sel[(size_t)si * 80 + (c - 330)];
        } else {
            val = f2c[(size_t)(BATCH + bi) * 50 + (c - 410)];
        }
        orow[c] = val;
    }
}

extern "C" void kernel_launch(void* const* d_in, const int* in_sizes, int n_in,
                              void* d_out, int out_size, void* d_ws, size_t ws_size,
                              hipStream_t stream) {
    const int*   userIdx = (const int*)d_in[0];
    const int*   itemIdx = (const int*)d_in[1];
    const int*   rows    = (const int*)d_in[2];
    const int*   cols    = (const int*)d_in[3];
    const float* vals    = (const float*)d_in[4];
    const float* uEmbd   = (const float*)d_in[5];
    const float* iEmbd   = (const float*)d_in[6];
    const float* w1      = (const float*)d_in[7];
    const float* b1      = (const float*)d_in[8];
    const float* wi1     = (const float*)d_in[9];
    const float* bi1     = (const float*)d_in[10];
    const float* w2      = (const float*)d_in[11];
    const float* b2      = (const float*)d_in[12];
    const float* wi2     = (const float*)d_in[13];
    const float* bi2     = (const float*)d_in[14];
    const float* t1w     = (const float*)d_in[15];
    const float* t1b     = (const float*)d_in[16];
    const float* t2w     = (const float*)d_in[17];
    const float* t2b     = (const float*)d_in[18];
    const float* t3w     = (const float*)d_in[19];
    const float* t3b     = (const float*)d_in[20];

    // ---- workspace layout (4-byte units) ----
    float* ws = (float*)d_ws;
    uint*  Xb64  = (uint*)ws;                  //  9,600,000 (MFMA A-stream, padded)
    uint*  Xc50  = (uint*)(ws + 9600000);      //  7,500,000 (compact gather copy)
    uint*  B1b   = (uint*)(ws + 17100000);     //  9,600,000 (padded)
    uint*  Lxb   = B1b;                        //  6,000,000 alias (B1b dead after gemm1)
    uint*  INTb  = (uint*)(ws + 26700000);     //  7,500,000
    uint*  F1b   = INTb;                       //  6,000,000 alias (INTb dead after pass2)
    uint*  B2b   = (uint*)(ws + 34200000);     //  9,600,000 (padded)
    uint*  wtW   = (uint*)(ws + 43800000);     //      5,120
    uint*  wtWi  = (uint*)(ws + 43805120);     //      5,120
    float* F1sel = ws + 43810240;              //    655,360
    float* Lxsel = ws + 44465600;              //    655,360
    float* B2c   = ws + 45120960;              //    655,360
    float* F2c   = ws + 45776320;              //    409,600
    float* EMB   = ws + 46185920;              //  1,884,160
    float* H1    = ws + 48070080;              //    262,144
    float* H2    = ws + 48332224;              //    131,072
    int*   deg   = (int*)(ws + 48463296);      //    150,000
    int*   ptr   = deg + 150000;
    int*   pos   = ptr + 150000;
    int*   bsum  = pos + 150000;               //      1,024
    int2*  ep    = (int2*)(bsum + 1024);       //  1,500,008 int2 (8-entry pad)
    int*   flag  = (int*)(ep + 1500008);       //    150,000
    int*   fpre  = flag + 150000;
    int*   list  = fpre + 150000;
    int*   bsum2 = list + 150000;              //      1,024
    int*   cnt   = bsum2 + 1024;
    int*   selMap= cnt + 1;                    //    150,000  (~210 MB total)

    const int E = N_EDGES;
    dim3 blk(256);

    // ---- prep: bf16 features (both layouts) + transposed bf16 weights ----
    cast_feats<<<(N_NODES * 64 + 255) / 256, blk, 0, stream>>>(uEmbd, iEmbd, Xb64, Xc50);
    prep_weights<<<(2 * 80 * 64 + 255) / 256, blk, 0, stream>>>(w1, wi1, wtW, wtWi);

    // ---- CSR build ----
    hipMemsetAsync(deg, 0, 150000 * sizeof(int), stream);
    hipMemsetAsync(flag, 0, 150000 * sizeof(int), stream);
    hipMemsetAsync(selMap, 0xFF, 150000 * sizeof(int), stream);
    hist_kernel<<<(E + 255) / 256, blk, 0, stream>>>(rows, deg, E);
    int nScanBlocks = (N_NODES + 255) / 256;            // 586
    scan_block<<<nScanBlocks, blk, 0, stream>>>(deg, ptr, bsum, N_NODES);
    scan_tops<<<1, dim3(1024), 0, stream>>>(bsum, nScanBlocks);
    scan_apply<<<nScanBlocks, blk, 0, stream>>>(ptr, bsum, pos, N_NODES);
    scatter_edges<<<(E + 255) / 256, blk, 0, stream>>>(rows, cols, vals, pos, ep, E);

    // ---- selMap + needed-row marking + compaction ----
    build_selmap<<<(2 * BATCH + 255) / 256, blk, 0, stream>>>(userIdx, itemIdx, selMap);
    mark_needed<<<(2 * BATCH + 3) / 4, blk, 0, stream>>>(
        userIdx, itemIdx, ptr, deg, ep, flag);
    scan_block<<<nScanBlocks, blk, 0, stream>>>(flag, fpre, bsum2, N_NODES);
    scan_tops<<<1, dim3(1024), 0, stream>>>(bsum2, nScanBlocks);
    compact_list<<<nScanBlocks, blk, 0, stream>>>(flag, fpre, bsum2, list, cnt, N_NODES);

    int rowGrid = (N_NODES + 3) / 4;
    int selGrid = (2 * BATCH + 3) / 4;

    // ---- Layer 1 (F = 100) ----
    spmm_pass1<<<rowGrid, blk, 0, stream>>>(ptr, deg, ep, Xc50, B1b, INTb, N_NODES);
    spmm_pass2<<<rowGrid, blk, 0, stream>>>(ptr, deg, ep, INTb, B2b, N_NODES);
    {
        int grid = (N_NODES + 63) / 64;
        gemm1_mfma<<<grid, blk, 0, stream>>>(
            B1b, Xb64, B2b, wtW, wtWi, b1, bi1, selMap,
            (ushort_t*)F1b, F1sel, N_NODES);
    }

    // ---- Layer 2 (F = 80) ----
    spmm_pass3<<<rowGrid, blk, 0, stream>>>(
        list, cnt, ptr, deg, ep, F1b, selMap, Lxb, Lxsel);
    spmm_pass4<<<selGrid, blk, 0, stream>>>(
        ptr, deg, ep, Lxb, F1b, userIdx, itemIdx, B2c);
    {
        int grid = (2 * BATCH + 127) / 128;
        gemm_fused2_sel<<<grid, blk, 0, stream>>>(
            Lxsel, F1sel, selMap, B2c, w2, b2, wi2, bi2, userIdx, itemIdx, F2c);
    }

    // ---- Gather + MLP ----
    gather_embd<<<BATCH, dim3(128), 0, stream>>>(
        userIdx, itemIdx, uEmbd, iEmbd, F1sel, selMap, F2c, EMB);
    {
        constexpr int TPR = 8;
        int grid = (BATCH + (256 / TPR) - 1) / (256 / TPR);
        mlp_gemm<460, 64, TPR, true><<<grid, blk, 0, stream>>>(
            EMB, t1w, t1b, H1, BATCH);
    }
    {
        constexpr int TPR = 4;
        int grid = (BATCH + (256 / TPR) - 1) / (256 / TPR);
        mlp_gemm<64, 32, TPR, false><<<grid, blk, 0, stream>>>(
            H1, t2w, t2b, H2, BATCH);
    }
    {
        constexpr int TPR = 1;
        int grid = (BATCH + 255) / 256;
        mlp_gemm<32, 1, TPR, false><<<grid, blk, 0, stream>>>(
            H2, t3w, t3b, (float*)d_out, BATCH);
    }
}

// Round 8
// 576.497 us; speedup vs baseline: 1.4043x; 1.0647x over previous
//
#include <hip/hip_runtime.h>

typedef unsigned int uint;
typedef unsigned short ushort_t;
typedef __attribute__((ext_vector_type(4))) float f32x4;
typedef __attribute__((ext_vector_type(8))) short bf16x8;

#define N_USERS 100000
#define N_ITEMS 50000
#define N_NODES 150000
#define N_EDGES 1500000
#define BATCH 4096
#define NSWEEP 4
#define SWEEP_ROWS 37500

__device__ __forceinline__ uint pack_bf16x2(float a, float b) {
    uint ua = __float_as_uint(a);
    uint ub = __float_as_uint(b);
    ua = (ua + 0x7FFFu + ((ua >> 16) & 1u)) >> 16;
    ub = (ub + 0x7FFFu + ((ub >> 16) & 1u)) >> 16;
    return ua | (ub << 16);
}
__device__ __forceinline__ ushort_t cvt_bf16(float a) {
    uint ua = __float_as_uint(a);
    return (ushort_t)((ua + 0x7FFFu + ((ua >> 16) & 1u)) >> 16);
}
__device__ __forceinline__ float bf_lo(uint u) { return __uint_as_float(u << 16); }
__device__ __forceinline__ float bf_hi(uint u) { return __uint_as_float(u & 0xFFFF0000u); }

// ===== 8-deep pipelined row gather-accumulate: sum_e v_e * src[col_e][lane] ====
// ep must be padded by >=16 entries past the last edge.
template<int P>
__device__ __forceinline__ float2 row_gather_accum(
    const int2* __restrict__ ep, int st, int d,
    const uint* __restrict__ src, int lane)
{
    float ax = 0.f, ay = 0.f;
    bool lok = lane < P;
    int2 e[12];
#pragma unroll
    for (int k = 0; k < 12; k++) e[k] = ep[st + k];
    uint b[8];
#pragma unroll
    for (int k = 0; k < 8; k++)
        b[k] = (lok && k < d) ? src[(size_t)e[k].x * P + lane] : 0u;
    for (int j = 0; j < d; j += 4) {
        uint n[4];
#pragma unroll
        for (int k = 0; k < 4; k++)
            n[k] = (lok && j + 8 + k < d) ? src[(size_t)e[8 + k].x * P + lane] : 0u;
        int2 ne[4];
#pragma unroll
        for (int k = 0; k < 4; k++) ne[k] = ep[st + j + 12 + k];
        {
            float v = __int_as_float(e[0].y);
            ax = fmaf(v, bf_lo(b[0]), ax);
            ay = fmaf(v, bf_hi(b[0]), ay);
        }
#pragma unroll
        for (int k = 1; k < 4; k++) {
            if (j + k < d) {
                float v = __int_as_float(e[k].y);
                ax = fmaf(v, bf_lo(b[k]), ax);
                ay = fmaf(v, bf_hi(b[k]), ay);
            }
        }
#pragma unroll
        for (int k = 0; k < 8; k++) e[k] = e[k + 4];
#pragma unroll
        for (int k = 0; k < 4; k++) { b[k] = b[k + 4]; b[k + 4] = n[k]; e[k + 8] = ne[k]; }
    }
    return make_float2(ax, ay);
}

// Dual-stream 4-deep variant: sum_e v_e * (A[col_e][lane] .* B[col_e][lane]), P=40
__device__ __forceinline__ float2 row_gather_accum_mul(
    const int2* __restrict__ ep, int st, int d,
    const uint* __restrict__ sA, const uint* __restrict__ sB, int lane)
{
    constexpr int P = 40;
    float ax = 0.f, ay = 0.f;
    bool lok = lane < P;
    int2 e0 = ep[st],     e1 = ep[st + 1], e2 = ep[st + 2], e3 = ep[st + 3];
    int2 e4 = ep[st + 4], e5 = ep[st + 5];
    uint a0 = (lok && 0 < d) ? sA[(size_t)e0.x * P + lane] : 0u;
    uint c0 = (lok && 0 < d) ? sB[(size_t)e0.x * P + lane] : 0u;
    uint a1 = (lok && 1 < d) ? sA[(size_t)e1.x * P + lane] : 0u;
    uint c1 = (lok && 1 < d) ? sB[(size_t)e1.x * P + lane] : 0u;
    uint a2 = (lok && 2 < d) ? sA[(size_t)e2.x * P + lane] : 0u;
    uint c2 = (lok && 2 < d) ? sB[(size_t)e2.x * P + lane] : 0u;
    uint a3 = (lok && 3 < d) ? sA[(size_t)e3.x * P + lane] : 0u;
    uint c3 = (lok && 3 < d) ? sB[(size_t)e3.x * P + lane] : 0u;
    for (int j = 0; j < d; j += 2) {
        uint nA4 = (lok && j + 4 < d) ? sA[(size_t)e4.x * P + lane] : 0u;
        uint nC4 = (lok && j + 4 < d) ? sB[(size_t)e4.x * P + lane] : 0u;
        uint nA5 = (lok && j + 5 < d) ? sA[(size_t)e5.x * P + lane] : 0u;
        uint nC5 = (lok && j + 5 < d) ? sB[(size_t)e5.x * P + lane] : 0u;
        int2 n6 = ep[st + j + 6];
        int2 n7 = ep[st + j + 7];
        float v0 = __int_as_float(e0.y);
        ax = fmaf(v0, bf_lo(a0) * bf_lo(c0), ax);
        ay = fmaf(v0, bf_hi(a0) * bf_hi(c0), ay);
        if (j + 1 < d) {
            float v1 = __int_as_float(e1.y);
            ax = fmaf(v1, bf_lo(a1) * bf_lo(c1), ax);
            ay = fmaf(v1, bf_hi(a1) * bf_hi(c1), ay);
        }
        e0 = e2; a0 = a2; c0 = c2; e1 = e3; a1 = a3; c1 = c3;
        e2 = e4; a2 = nA4; c2 = nC4; e3 = e5; a3 = nA5; c3 = nC5;
        e4 = n6; e5 = n7;
    }
    return make_float2(ax, ay);
}

// ============ bf16 feature cast: padded (stride 64) + compact (stride 50) =====
__global__ __launch_bounds__(256) void cast_feats(
    const float* __restrict__ uE, const float* __restrict__ iE,
    uint* __restrict__ Xb64, uint* __restrict__ Xc50)
{
    int g = blockIdx.x * 256 + threadIdx.x;
    if (g >= N_NODES * 64) return;
    int row = g >> 6, c = g & 63;
    uint outv = 0u;
    if (c < 50) {
        int e0 = c * 2;
        float a, b;
        if (row < N_USERS) { a = uE[(size_t)row * 100 + e0]; b = uE[(size_t)row * 100 + e0 + 1]; }
        else { a = iE[(size_t)(row - N_USERS) * 100 + e0]; b = iE[(size_t)(row - N_USERS) * 100 + e0 + 1]; }
        outv = pack_bf16x2(a, b);
        Xc50[(size_t)row * 50 + c] = outv;
    }
    Xb64[g] = outv;
}

// ============ weight prep: wT bf16 [80 cols][64 uints=128 k, zero-padded] =====
__global__ __launch_bounds__(256) void prep_weights(
    const float* __restrict__ W, const float* __restrict__ Wi,
    uint* __restrict__ wtW, uint* __restrict__ wtWi)
{
    int t = blockIdx.x * 256 + threadIdx.x;
    if (t >= 2 * 80 * 64) return;
    const float* src = (t < 80 * 64) ? W : Wi;
    uint* dst = (t < 80 * 64) ? wtW : wtWi;
    int i = t % (80 * 64);
    int col = i >> 6, kk = i & 63;
    int k = kk * 2;
    uint v = 0u;
    if (k < 100) v = pack_bf16x2(src[(size_t)k * 80 + col], src[(size_t)(k + 1) * 80 + col]);
    dst[(size_t)col * 64 + kk] = v;
}

// ======================= CSR construction =======================
__global__ __launch_bounds__(256) void hist_kernel(
    const int* __restrict__ rows, int* __restrict__ deg, int E)
{
    int e = blockIdx.x * 256 + threadIdx.x;
    if (e < E) atomicAdd(&deg[rows[e]], 1);
}

__global__ __launch_bounds__(256) void scan_block(
    const int* __restrict__ deg, int* __restrict__ ptr,
    int* __restrict__ bsum, int n)
{
    __shared__ int s[256];
    int t = threadIdx.x;
    int i = blockIdx.x * 256 + t;
    int v = (i < n) ? deg[i] : 0;
    s[t] = v; __syncthreads();
    for (int off = 1; off < 256; off <<= 1) {
        int x = (t >= off) ? s[t - off] : 0;
        __syncthreads();
        s[t] += x;
        __syncthreads();
    }
    if (i < n) ptr[i] = s[t] - v;
    if (t == 255) bsum[blockIdx.x] = s[255];
}

__global__ __launch_bounds__(1024) void scan_tops(int* __restrict__ bsum, int nb)
{
    __shared__ int s[1024];
    int t = threadIdx.x;
    int v = (t < nb) ? bsum[t] : 0;
    s[t] = v; __syncthreads();
    for (int off = 1; off < 1024; off <<= 1) {
        int x = (t >= off) ? s[t - off] : 0;
        __syncthreads();
        s[t] += x;
        __syncthreads();
    }
    if (t < nb) bsum[t] = s[t] - v;
}

__global__ __launch_bounds__(256) void scan_apply(
    int* __restrict__ ptr, const int* __restrict__ bsum,
    int* __restrict__ pos, int n)
{
    int i = blockIdx.x * 256 + threadIdx.x;
    if (i < n) {
        int p = ptr[i] + bsum[i >> 8];
        ptr[i] = p;
        pos[i] = p;
    }
}

// Swept scatter: only rows in [lo,hi) — keeps active ep window L2-resident so
// same-line writes coalesce in L2 (kills the 8x HBM write amplification).
__global__ __launch_bounds__(256) void scatter_sweep(
    const int* __restrict__ rows, const int* __restrict__ cols,
    const float* __restrict__ vals, int* __restrict__ pos,
    int2* __restrict__ ep, int E, int lo, int hi)
{
    int e = blockIdx.x * 256 + threadIdx.x;
    if (e >= E) return;
    int r = rows[e];
    if (r < lo || r >= hi) return;
    int p = atomicAdd(&pos[r], 1);
    ep[p] = make_int2(cols[e], __float_as_int(vals[e]));
}

// ============== selMap + needed-row marking =====================
__global__ __launch_bounds__(256) void build_selmap(
    const int* __restrict__ userIdx, const int* __restrict__ itemIdx,
    int* __restrict__ selMap)
{
    int i = blockIdx.x * 256 + threadIdx.x;
    if (i < BATCH) selMap[userIdx[i]] = i;
    else if (i < 2 * BATCH) selMap[itemIdx[i - BATCH]] = i;
}

__global__ __launch_bounds__(256) void mark_needed(
    const int* __restrict__ userIdx, const int* __restrict__ itemIdx,
    const int* __restrict__ ptr_, const int* __restrict__ deg_,
    const int2* __restrict__ ep, int* __restrict__ flag)
{
    int i = blockIdx.x * 4 + ((int)threadIdx.x >> 6);
    if (i >= 2 * BATCH) return;
    int lane = threadIdx.x & 63;
    int row = (i < BATCH) ? userIdx[i] : itemIdx[i - BATCH];
    if (lane == 0) flag[row] = 1;
    int st = ptr_[row], d = deg_[row];
    for (int j = lane; j < d; j += 64)
        flag[ep[st + j].x] = 1;
}

__global__ __launch_bounds__(256) void compact_list(
    const int* __restrict__ flag, const int* __restrict__ fpre,
    const int* __restrict__ bsum, int* __restrict__ list,
    int* __restrict__ count, int n)
{
    int i = blockIdx.x * 256 + threadIdx.x;
    if (i < n) {
        int base = fpre[i] + bsum[i >> 8];
        if (flag[i]) list[base] = i;
        if (i == n - 1) *count = base + flag[i];
    }
}

// ======================= SpMM kernels (bf16 gather, pipelined) =================

// Pass 1 (F=100): B1b64 = bf16(L@X) padded; INTb50 = bf16((L@X) .* X)
__global__ __launch_bounds__(256) void spmm_pass1(
    const int* __restrict__ ptr_, const int* __restrict__ deg_,
    const int2* __restrict__ ep, const uint* __restrict__ Xc,
    uint* __restrict__ B1b, uint* __restrict__ INTb, int N)
{
    int row = blockIdx.x * 4 + ((int)threadIdx.x >> 6);
    if (row >= N) return;
    int lane = threadIdx.x & 63;
    float2 r = row_gather_accum<50>(ep, ptr_[row], deg_[row], Xc, lane);
    B1b[(size_t)row * 64 + lane] = pack_bf16x2(r.x, r.y);   // pad lanes pack 0
    if (lane < 50) {
        uint xb = Xc[(size_t)row * 50 + lane];
        INTb[(size_t)row * 50 + lane] = pack_bf16x2(r.x * bf_lo(xb), r.y * bf_hi(xb));
    }
}

// Pass 2 (F=100): B2b64 = bf16(L @ INTb) padded
__global__ __launch_bounds__(256) void spmm_pass2(
    const int* __restrict__ ptr_, const int* __restrict__ deg_,
    const int2* __restrict__ ep, const uint* __restrict__ INTb,
    uint* __restrict__ B2b, int N)
{
    int row = blockIdx.x * 4 + ((int)threadIdx.x >> 6);
    if (row >= N) return;
    int lane = threadIdx.x & 63;
    float2 r = row_gather_accum<50>(ep, ptr_[row], deg_[row], INTb, lane);
    B2b[(size_t)row * 64 + lane] = pack_bf16x2(r.x, r.y);
}

// Pass 3 (F=80): Lx2 = L@F1 over needed list; writes bf16 Lxb40 + fp32 Lxsel
__global__ __launch_bounds__(256) void spmm_pass3(
    const int* __restrict__ list, const int* __restrict__ count,
    const int* __restrict__ ptr_, const int* __restrict__ deg_,
    const int2* __restrict__ ep, const uint* __restrict__ F1b,
    const int* __restrict__ selMap,
    uint* __restrict__ Lxb, float* __restrict__ Lxsel)
{
    int idx = blockIdx.x * 4 + ((int)threadIdx.x >> 6);
    if (idx >= *count) return;
    int row = list[idx];
    int lane = threadIdx.x & 63;
    float2 r = row_gather_accum<40>(ep, ptr_[row], deg_[row], F1b, lane);
    if (lane < 40) {
        Lxb[(size_t)row * 40 + lane] = pack_bf16x2(r.x, r.y);
        int sm = selMap[row];
        if (sm >= 0)
            ((float2*)(Lxsel + (size_t)sm * 80))[lane] = r;
    }
}

// Pass 4 (selected rows): B2c[i] = sum_e v * (Lx2[c] .* F1[c]), both bf16
__global__ __launch_bounds__(256) void spmm_pass4(
    const int* __restrict__ ptr_, const int* __restrict__ deg_,
    const int2* __restrict__ ep,
    const uint* __restrict__ Lxb, const uint* __restrict__ F1b,
    const int* __restrict__ userIdx, const int* __restrict__ itemIdx,
    float* __restrict__ outC)
{
    int i = blockIdx.x * 4 + ((int)threadIdx.x >> 6);
    if (i >= 2 * BATCH) return;
    int row = (i < BATCH) ? userIdx[i] : itemIdx[i - BATCH];
    int lane = threadIdx.x & 63;
    float2 r = row_gather_accum_mul(ep, ptr_[row], deg_[row], Lxb, F1b, lane);
    if (lane < 40)
        ((float2*)(outC + (size_t)i * 80))[lane] = r;
}

// ------------- Layer-1 fused linear via MFMA ------------------------------
__global__ __launch_bounds__(256) void gemm1_mfma(
    const uint* __restrict__ B1b, const uint* __restrict__ Xb,
    const uint* __restrict__ B2b,
    const uint* __restrict__ wtW, const uint* __restrict__ wtWi,
    const float* __restrict__ b, const float* __restrict__ bi,
    const int* __restrict__ selMap,
    ushort_t* __restrict__ F1b, float* __restrict__ F1sel, int N)
{
    int wave = (int)threadIdx.x >> 6;
    int lane = (int)threadIdx.x & 63;
    int rowBase = blockIdx.x * 64 + wave * 16;
    int colLocal = lane & 15;
    int q = lane >> 4;
    int arow = rowBase + colLocal;
    bool rowOK = arow < N;

    f32x4 acc[5];
#pragma unroll
    for (int nt = 0; nt < 5; nt++) acc[nt] = (f32x4){0.f, 0.f, 0.f, 0.f};

    const bf16x8 zfrag = {};
    size_t aoff = (size_t)arow * 64 + q * 4;

#pragma unroll
    for (int ks = 0; ks < 4; ks++) {
        bf16x8 aL = rowOK ? *(const bf16x8*)(B1b + aoff + ks * 16) : zfrag;
        bf16x8 aX = rowOK ? *(const bf16x8*)(Xb  + aoff + ks * 16) : zfrag;
        bf16x8 aS = rowOK ? *(const bf16x8*)(B2b + aoff + ks * 16) : zfrag;
#pragma unroll
        for (int nt = 0; nt < 5; nt++) {
            size_t boff = (size_t)(nt * 16 + colLocal) * 64 + ks * 16 + q * 4;
            bf16x8 bW  = *(const bf16x8*)(wtW  + boff);
            bf16x8 bWi = *(const bf16x8*)(wtWi + boff);
            acc[nt] = __builtin_amdgcn_mfma_f32_16x16x32_bf16(aL, bW,  acc[nt], 0, 0, 0);
            acc[nt] = __builtin_amdgcn_mfma_f32_16x16x32_bf16(aX, bW,  acc[nt], 0, 0, 0);
            acc[nt] = __builtin_amdgcn_mfma_f32_16x16x32_bf16(aS, bWi, acc[nt], 0, 0, 0);
        }
    }

    int sm[4];
    bool rok[4];
#pragma unroll
    for (int reg = 0; reg < 4; reg++) {
        int row = rowBase + q * 4 + reg;
        rok[reg] = row < N;
        sm[reg] = rok[reg] ? selMap[row] : -1;
    }
#pragma unroll
    for (int nt = 0; nt < 5; nt++) {
        int col = nt * 16 + colLocal;
        float bias = b[col] + bi[col];
#pragma unroll
        for (int reg = 0; reg < 4; reg++) {
            if (!rok[reg]) continue;
            int row = rowBase + q * 4 + reg;
            float v = fmaxf(acc[nt][reg] + bias, 0.f);
            F1b[(size_t)row * 80 + col] = cvt_bf16(v);
            if (sm[reg] >= 0) F1sel[(size_t)sm[reg] * 80 + col] = v;
        }
    }
}

// Layer-2 fused GEMM restricted to sampled rows; Lx and X via compact buffers.
__global__ __launch_bounds__(256) void gemm_fused2_sel(
    const float* __restrict__ Lxsel, const float* __restrict__ F1sel,
    const int* __restrict__ selMap,
    const float* __restrict__ S2c,
    const float* __restrict__ W, const float* __restrict__ b,
    const float* __restrict__ Wi, const float* __restrict__ bi,
    const int* __restrict__ userIdx, const int* __restrict__ itemIdx,
    float* __restrict__ outC)
{
    constexpr int K = 80, M = 50, TPR = 2, MT = M / TPR;
    __shared__ float sW[K * M];
    __shared__ float sWi[K * M];
    for (int i = threadIdx.x; i < K * M; i += 256) {
        sW[i]  = W[i];
        sWi[i] = Wi[i];
    }
    __syncthreads();

    int i = blockIdx.x * (256 / TPR) + (int)threadIdx.x / TPR;
    int mBase = ((int)threadIdx.x % TPR) * MT;
    if (i >= 2 * BATCH) return;
    int r = (i < BATCH) ? userIdx[i] : itemIdx[i - BATCH];
    int sm = selMap[r];

    const float* xrow = F1sel + (size_t)sm * K;
    const float* lrow = Lxsel + (size_t)sm * K;
    const float* srow = S2c + (size_t)i * K;

    float acc[MT];
#pragma unroll
    for (int m = 0; m < MT; m++) acc[m] = 0.0f;

    for (int k4 = 0; k4 < K; k4 += 4) {
        float4 lv = *(const float4*)(lrow + k4);
        float4 xv = *(const float4*)(xrow + k4);
        float4 sv = *(const float4*)(srow + k4);
        float a[4] = {lv.x + xv.x, lv.y + xv.y, lv.z + xv.z, lv.w + xv.w};
        float s[4] = {sv.x, sv.y, sv.z, sv.w};
#pragma unroll
        for (int kk = 0; kk < 4; kk++) {
            const float* wk  = &sW[(k4 + kk) * M + mBase];
            const float* wik = &sWi[(k4 + kk) * M + mBase];
#pragma unroll
            for (int m = 0; m < MT; m++)
                acc[m] = fmaf(a[kk], wk[m], fmaf(s[kk], wik[m], acc[m]));
        }
    }

    float* orow = outC + (size_t)i * M + mBase;
#pragma unroll
    for (int m = 0; m < MT; m++)
        orow[m] = fmaxf(acc[m] + b[mBase + m] + bi[mBase + m], 0.0f);
}

// ------------- Plain MLP GEMM ---------------------------------------------
template<int K, int M, int TPR, bool RELU>
__global__ __launch_bounds__(256) void mlp_gemm(
    const float* __restrict__ A,
    const float* __restrict__ W, const float* __restrict__ b,
    float* __restrict__ out, int N)
{
    __shared__ float sW[K * M];
    for (int i = threadIdx.x; i < K * M; i += 256) sW[i] = W[i];
    __syncthreads();

    constexpr int RPB = 256 / TPR;
    constexpr int MT  = M / TPR;
    int r = blockIdx.x * RPB + (int)threadIdx.x / TPR;
    int mBase = ((int)threadIdx.x % TPR) * MT;
    if (r >= N) return;

    const float* arow = A + (size_t)r * K;
    float acc[MT];
#pragma unroll
    for (int m = 0; m < MT; m++) acc[m] = 0.0f;

    for (int k = 0; k < K; k++) {
        float a = arow[k];
#pragma unroll
        for (int m = 0; m < MT; m++)
            acc[m] = fmaf(a, sW[k * M + mBase + m], acc[m]);
    }

    float* orow = out + (size_t)r * M + mBase;
#pragma unroll
    for (int m = 0; m < MT; m++) {
        float vv = acc[m] + b[mBase + m];
        orow[m] = RELU ? fmaxf(vv, 0.0f) : vv;
    }
}

// ------------- Gather final embeddings into [BATCH, 460] ------------------
__global__ __launch_bounds__(128) void gather_embd(
    const int* __restrict__ userIdx, const int* __restrict__ itemIdx,
    const float* __restrict__ uE, const float* __restrict__ iE,
    const float* __restrict__ F1sel, const int* __restrict__ selMap,
    const float* __restrict__ f2c,
    float* __restrict__ emb)
{
    int bi = blockIdx.x;
    int u  = userIdx[bi];
    int it = itemIdx[bi];
    int su = selMap[u];
    int si = selMap[it];
    float* orow = emb + (size_t)bi * 460;
    for (int c = threadIdx.x; c < 460; c += 128) {
        float val;
        if (c < 100) {
            val = (u < N_USERS) ? uE[(size_t)u * 100 + c]
                                : iE[(size_t)(u - N_USERS) * 100 + c];
        } else if (c < 180) {
            val = F1sel[(size_t)su * 80 + (c - 100)];
        } else if (c < 230) {
            val = f2c[(size_t)bi * 50 + (c - 180)];
        } else if (c < 330) {
            int cc = c - 230;
            val = (it < N_USERS) ? uE[(size_t)it * 100 + cc]
                                 : iE[(size_t)(it - N_USERS) * 100 + cc];
        } else if (c < 410) {
            val = F1sel[(size_t)si * 80 + (c - 330)];
        } else {
            val = f2c[(size_t)(BATCH + bi) * 50 + (c - 410)];
        }
        orow[c] = val;
    }
}

extern "C" void kernel_launch(void* const* d_in, const int* in_sizes, int n_in,
                              void* d_out, int out_size, void* d_ws, size_t ws_size,
                              hipStream_t stream) {
    const int*   userIdx = (const int*)d_in[0];
    const int*   itemIdx = (const int*)d_in[1];
    const int*   rows    = (const int*)d_in[2];
    const int*   cols    = (const int*)d_in[3];
    const float* vals    = (const float*)d_in[4];
    const float* uEmbd   = (const float*)d_in[5];
    const float* iEmbd   = (const float*)d_in[6];
    const float* w1      = (const float*)d_in[7];
    const float* b1      = (const float*)d_in[8];
    const float* wi1     = (const float*)d_in[9];
    const float* bi1     = (const float*)d_in[10];
    const float* w2      = (const float*)d_in[11];
    const float* b2      = (const float*)d_in[12];
    const float* wi2     = (const float*)d_in[13];
    const float* bi2     = (const float*)d_in[14];
    const float* t1w     = (const float*)d_in[15];
    const float* t1b     = (const float*)d_in[16];
    const float* t2w     = (const float*)d_in[17];
    const float* t2b     = (const float*)d_in[18];
    const float* t3w     = (const float*)d_in[19];
    const float* t3b     = (const float*)d_in[20];

    // ---- workspace layout (4-byte units) ----
    float* ws = (float*)d_ws;
    uint*  Xb64  = (uint*)ws;                  //  9,600,000 (MFMA A-stream, padded)
    uint*  Xc50  = (uint*)(ws + 9600000);      //  7,500,000 (compact gather copy)
    uint*  B1b   = (uint*)(ws + 17100000);     //  9,600,000 (padded)
    uint*  Lxb   = B1b;                        //  6,000,000 alias (B1b dead after gemm1)
    uint*  INTb  = (uint*)(ws + 26700000);     //  7,500,000
    uint*  F1b   = INTb;                       //  6,000,000 alias (INTb dead after pass2)
    uint*  B2b   = (uint*)(ws + 34200000);     //  9,600,000 (padded)
    uint*  wtW   = (uint*)(ws + 43800000);     //      5,120
    uint*  wtWi  = (uint*)(ws + 43805120);     //      5,120
    float* F1sel = ws + 43810240;              //    655,360
    float* Lxsel = ws + 44465600;              //    655,360
    float* B2c   = ws + 45120960;              //    655,360
    float* F2c   = ws + 45776320;              //    409,600
    float* EMB   = ws + 46185920;              //  1,884,160
    float* H1    = ws + 48070080;              //    262,144
    float* H2    = ws + 48332224;              //    131,072
    int*   deg   = (int*)(ws + 48463296);      //    150,000
    int*   ptr   = deg + 150000;
    int*   pos   = ptr + 150000;
    int*   bsum  = pos + 150000;               //      1,024
    int2*  ep    = (int2*)(bsum + 1024);       //  1,500,016 int2 (16-entry pad)
    int*   flag  = (int*)(ep + 1500016);       //    150,000
    int*   fpre  = flag + 150000;
    int*   list  = fpre + 150000;
    int*   bsum2 = list + 150000;              //      1,024
    int*   cnt   = bsum2 + 1024;
    int*   selMap= cnt + 1;                    //    150,000  (~210 MB total)

    const int E = N_EDGES;
    dim3 blk(256);

    // ---- prep: bf16 features (both layouts) + transposed bf16 weights ----
    cast_feats<<<(N_NODES * 64 + 255) / 256, blk, 0, stream>>>(uEmbd, iEmbd, Xb64, Xc50);
    prep_weights<<<(2 * 80 * 64 + 255) / 256, blk, 0, stream>>>(w1, wi1, wtW, wtWi);

    // ---- CSR build ----
    hipMemsetAsync(deg, 0, 150000 * sizeof(int), stream);
    hipMemsetAsync(flag, 0, 150000 * sizeof(int), stream);
    hipMemsetAsync(selMap, 0xFF, 150000 * sizeof(int), stream);
    hist_kernel<<<(E + 255) / 256, blk, 0, stream>>>(rows, deg, E);
    int nScanBlocks = (N_NODES + 255) / 256;            // 586
    scan_block<<<nScanBlocks, blk, 0, stream>>>(deg, ptr, bsum, N_NODES);
    scan_tops<<<1, dim3(1024), 0, stream>>>(bsum, nScanBlocks);
    scan_apply<<<nScanBlocks, blk, 0, stream>>>(ptr, bsum, pos, N_NODES);
    for (int s = 0; s < NSWEEP; s++) {
        scatter_sweep<<<(E + 255) / 256, blk, 0, stream>>>(
            rows, cols, vals, pos, ep, E, s * SWEEP_ROWS, (s + 1) * SWEEP_ROWS);
    }

    // ---- selMap + needed-row marking + compaction ----
    build_selmap<<<(2 * BATCH + 255) / 256, blk, 0, stream>>>(userIdx, itemIdx, selMap);
    mark_needed<<<(2 * BATCH + 3) / 4, blk, 0, stream>>>(
        userIdx, itemIdx, ptr, deg, ep, flag);
    scan_block<<<nScanBlocks, blk, 0, stream>>>(flag, fpre, bsum2, N_NODES);
    scan_tops<<<1, dim3(1024), 0, stream>>>(bsum2, nScanBlocks);
    compact_list<<<nScanBlocks, blk, 0, stream>>>(flag, fpre, bsum2, list, cnt, N_NODES);

    int rowGrid = (N_NODES + 3) / 4;
    int selGrid = (2 * BATCH + 3) / 4;

    // ---- Layer 1 (F = 100) ----
    spmm_pass1<<<rowGrid, blk, 0, stream>>>(ptr, deg, ep, Xc50, B1b, INTb, N_NODES);
    spmm_pass2<<<rowGrid, blk, 0, stream>>>(ptr, deg, ep, INTb, B2b, N_NODES);
    {
        int grid = (N_NODES + 63) / 64;
        gemm1_mfma<<<grid, blk, 0, stream>>>(
            B1b, Xb64, B2b, wtW, wtWi, b1, bi1, selMap,
            (ushort_t*)F1b, F1sel, N_NODES);
    }

    // ---- Layer 2 (F = 80) ----
    spmm_pass3<<<rowGrid, blk, 0, stream>>>(
        list, cnt, ptr, deg, ep, F1b, selMap, Lxb, Lxsel);
    spmm_pass4<<<selGrid, blk, 0, stream>>>(
        ptr, deg, ep, Lxb, F1b, userIdx, itemIdx, B2c);
    {
        int grid = (2 * BATCH + 127) / 128;
        gemm_fused2_sel<<<grid, blk, 0, stream>>>(
            Lxsel, F1sel, selMap, B2c, w2, b2, wi2, bi2, userIdx, itemIdx, F2c);
    }

    // ---- Gather + MLP ----
    gather_embd<<<BATCH, dim3(128), 0, stream>>>(
        userIdx, itemIdx, uEmbd, iEmbd, F1sel, selMap, F2c, EMB);
    {
        constexpr int TPR = 8;
        int grid = (BATCH + (256 / TPR) - 1) / (256 / TPR);
        mlp_gemm<460, 64, TPR, true><<<grid, blk, 0, stream>>>(
            EMB, t1w, t1b, H1, BATCH);
    }
    {
        constexpr int TPR = 4;
        int grid = (BATCH + (256 / TPR) - 1) / (256 / TPR);
        mlp_gemm<64, 32, TPR, false><<<grid, blk, 0, stream>>>(
            H1, t2w, t2b, H2, BATCH);
    }
    {
        constexpr int TPR = 1;
        int grid = (BATCH + 255) / 256;
        mlp_gemm<32, 1, TPR, false><<<grid, blk, 0, stream>>>(
            H2, t3w, t3b, (float*)d_out, BATCH);
    }
}